// Round 10
// baseline (658.781 us; speedup 1.0000x reference)
//
#include <hip/hip_runtime.h>
#include <math.h>

#define NN 10000
#define NE 40000
#define NGRAPH 64
#define HID 64
#define EDIM 16
#define NLAYERS 3
#define MT 16               // node tile of k_bgemm
#define NCH 2500            // B chunk: 41 MB, L3-resident

__device__ __forceinline__ float silu_f(float x) { return x / (1.f + expf(-x)); }

// ---------------- small row GEMM: out[M][64] = act(A[M][K] @ W[K][64] + bias) ----
template<int K, bool DO_SILU, bool HAS_BIAS>
__global__ __launch_bounds__(256)
void k_rowmm(const float* __restrict__ A, const float* __restrict__ W,
             const float* __restrict__ bias, float* __restrict__ out, int M) {
    __shared__ float Ws[K * 64];
    __shared__ float As[4 * K];
    const int tid = threadIdx.x;
    for (int idx = tid; idx < K * 64; idx += 256) Ws[idx] = W[idx];
    const int r0 = blockIdx.x * 4;
    for (int idx = tid; idx < 4 * K; idx += 256) {
        int r = r0 + idx / K;
        As[idx] = (r < M) ? A[(size_t)r * K + (idx % K)] : 0.f;
    }
    __syncthreads();
    const int rr = tid >> 6, c = tid & 63;
    const int r = r0 + rr;
    if (r >= M) return;
    float s = HAS_BIAS ? bias[c] : 0.f;
#pragma unroll
    for (int k = 0; k < K; k++) s += As[rr * K + k] * Ws[k * 64 + c];
    if (DO_SILU) s = silu_f(s);
    out[(size_t)r * 64 + c] = s;
}

// ---------------- degree histograms (src + dst) ----------------
__global__ void k_hist(const int* __restrict__ ei, int* __restrict__ cnt_s,
                       int* __restrict__ cnt_d) {
    int e = blockIdx.x * 256 + threadIdx.x;
    if (e >= NE) return;
    atomicAdd(&cnt_s[ei[e]], 1);
    atomicAdd(&cnt_d[ei[NE + e]], 1);
}

__global__ void k_invdeg(const int* __restrict__ cnt_d, float* __restrict__ invd) {
    int n = blockIdx.x * 256 + threadIdx.x;
    if (n < NN) {
        int d = cnt_d[n];
        invd[n] = (d > 0) ? 1.f / (float)d : 0.f;
    }
}

// ---------------- single-block exclusive scan over NN counts ----------------
__global__ __launch_bounds__(1024)
void k_scan(const int* __restrict__ cnt, int* __restrict__ off, int* __restrict__ cur) {
    __shared__ int part[1024];
    const int t = threadIdx.x;
    const int CH = (NN + 1023) / 1024;  // 10
    const int base0 = t * CH;
    int s = 0;
    for (int i = 0; i < CH; i++) {
        int idx = base0 + i;
        if (idx < NN) s += cnt[idx];
    }
    part[t] = s;
    __syncthreads();
    for (int d = 1; d < 1024; d <<= 1) {
        int v = (t >= d) ? part[t - d] : 0;
        __syncthreads();
        part[t] += v;
        __syncthreads();
    }
    int run = (t == 0) ? 0 : part[t - 1];
    for (int i = 0; i < CH; i++) {
        int idx = base0 + i;
        if (idx < NN) {
            off[idx] = run;
            run += cnt[idx];
            cur[idx] = 0;
        }
    }
    if (t == 1023) off[NN] = run;
}

__global__ void k_fill(const int* __restrict__ keys, const int* __restrict__ off,
                       int* __restrict__ cur, int* __restrict__ eid) {
    int e = blockIdx.x * 256 + threadIdx.x;
    if (e >= NE) return;
    int s = keys[e];
    int p = atomicAdd(&cur[s], 1);
    eid[off[s] + p] = e;
}

// ---------------- B-chunk GEMM v3: thread tile 16j x 2k, pipe-balanced ----------
// grid (ceil(n/16), 8); block 256 = 4 waves; thread (kq = tid>>6, o = lane),
// k = kb*8 + kq*2 + {0,1}. Per iter: 2 global w + 4 ds_read_b128 + 32 FMA.
__global__ __launch_bounds__(256, 4)
void k_bgemm(const float* __restrict__ h, const float* __restrict__ w2,
             float* __restrict__ B, int n0, int n1) {
    __shared__ float h_s[64 * MT];   // [i][j], writes j-fast -> conflict-free
    const int tid = threadIdx.x;
    const int mb = blockIdx.x, kb = blockIdx.y;
    const int row0 = n0 + mb * MT;
#pragma unroll
    for (int idx = tid; idx < 64 * MT; idx += 256) {
        const int j = idx & 15, i = idx >> 4;
        const int row = row0 + j;
        h_s[i * MT + j] = (row < n1) ? h[(size_t)row * 64 + i] : 0.f;
    }
    __syncthreads();

    const int kq = tid >> 6;           // 0..3
    const int o  = tid & 63;
    const int k0 = kb * 8 + kq * 2;
    const float* w2p0 = w2 + (size_t)k0 * 4096 + o;     // dense 256B wave loads
    const float* w2p1 = w2p0 + 4096;

    float a0[MT], a1[MT];
#pragma unroll
    for (int j = 0; j < MT; ++j) { a0[j] = 0.f; a1[j] = 0.f; }

#pragma unroll 2
    for (int i = 0; i < 64; ++i) {
        const float w0 = w2p0[i * 64];
        const float w1 = w2p1[i * 64];
        const float* hr = h_s + i * MT;
        const float4 h0 = *(const float4*)(hr);         // broadcast reads
        const float4 h1 = *(const float4*)(hr + 4);
        const float4 h2 = *(const float4*)(hr + 8);
        const float4 h3 = *(const float4*)(hr + 12);
        a0[0]  += w0 * h0.x; a0[1]  += w0 * h0.y; a0[2]  += w0 * h0.z; a0[3]  += w0 * h0.w;
        a0[4]  += w0 * h1.x; a0[5]  += w0 * h1.y; a0[6]  += w0 * h1.z; a0[7]  += w0 * h1.w;
        a0[8]  += w0 * h2.x; a0[9]  += w0 * h2.y; a0[10] += w0 * h2.z; a0[11] += w0 * h2.w;
        a0[12] += w0 * h3.x; a0[13] += w0 * h3.y; a0[14] += w0 * h3.z; a0[15] += w0 * h3.w;
        a1[0]  += w1 * h0.x; a1[1]  += w1 * h0.y; a1[2]  += w1 * h0.z; a1[3]  += w1 * h0.w;
        a1[4]  += w1 * h1.x; a1[5]  += w1 * h1.y; a1[6]  += w1 * h1.z; a1[7]  += w1 * h1.w;
        a1[8]  += w1 * h2.x; a1[9]  += w1 * h2.y; a1[10] += w1 * h2.z; a1[11] += w1 * h2.w;
        a1[12] += w1 * h3.x; a1[13] += w1 * h3.y; a1[14] += w1 * h3.z; a1[15] += w1 * h3.w;
    }
    float* Bp = B + ((size_t)mb * MT) * 4096 + k0 * 64 + o;   // dense 256B stores
#pragma unroll
    for (int j = 0; j < MT; ++j) {
        Bp[(size_t)j * 4096]      = a0[j];
        Bp[(size_t)j * 4096 + 64] = a1[j];
    }
}

// ---------------- src-grouped edge kernel: wave per source node ----------------
__global__ __launch_bounds__(256, 1)
void k_edge2(const float* __restrict__ g, const float* __restrict__ B,
             const float* __restrict__ Cbuf, const int* __restrict__ off_s,
             const int* __restrict__ eid_s, float* __restrict__ msg,
             int n0, int nCnt) {
    const int widx = blockIdx.x * 4 + (threadIdx.x >> 6);
    if (widx >= nCnt) return;
    const int n = n0 + widx;
    const int o = threadIdx.x & 63;
    const int p0 = off_s[n], p1 = off_s[n + 1];
    if (p0 == p1) return;                       // no out-edges: skip B load
    const float* Brow = B + (size_t)widx * 4096 + o;
    float b[64];
#pragma unroll
    for (int k = 0; k < 64; ++k) b[k] = Brow[k * 64];   // dense 256B wave loads
    const float cv = Cbuf[(size_t)n * 64 + o];
    for (int p = p0; p < p1; ++p) {
        const int e = __builtin_amdgcn_readfirstlane(eid_s[p]);
        const float* grow = g + (size_t)e * 64;          // uniform -> scalar loads
        float m = cv;
#pragma unroll
        for (int k = 0; k < 64; ++k) m += grow[k] * b[k];
        msg[(size_t)e * 64 + o] = m;
    }
}

// ---------------- gather by dst + root GEMM + silu ----------------
__global__ __launch_bounds__(256)
void k_aggfin(const float* __restrict__ h, const float* __restrict__ msg,
              const int* __restrict__ off2, const int* __restrict__ eid2,
              const float* __restrict__ invd, const float* __restrict__ rw,
              const float* __restrict__ cb, float* __restrict__ hout) {
    __shared__ float Ws[64 * 64];
    __shared__ float As[4 * 64];
    __shared__ int eoff[5];
    const int tid = threadIdx.x;
    for (int idx = tid; idx < 64 * 64; idx += 256) Ws[idx] = rw[idx];
    const int r0 = blockIdx.x * 4;
    As[tid] = h[(size_t)r0 * 64 + tid];
    if (tid < 5) eoff[tid] = off2[r0 + tid];
    __syncthreads();
    const int rr = tid >> 6, c = tid & 63;
    const int r = r0 + rr;
    float a = 0.f;
    for (int p = eoff[rr]; p < eoff[rr + 1]; ++p) {
        const int e = eid2[p];
        a += msg[(size_t)e * 64 + c];
    }
    float s = cb[c] + a * invd[r];
#pragma unroll
    for (int k = 0; k < 64; k++) s += As[rr * 64 + k] * Ws[k * 64 + c];
    hout[(size_t)r * 64 + c] = silu_f(s);
}

// ---------------- fused mean-pool + head MLP (no atomics) ----------------
__global__ __launch_bounds__(256)
void k_poolhead(const float* __restrict__ h, const int* __restrict__ batch,
                const float* __restrict__ w1, const float* __restrict__ b1,
                const float* __restrict__ w2, const float* __restrict__ b2,
                float* __restrict__ out) {
    __shared__ float part[4 * 64];
    __shared__ float hrow[64];
    const int gidx = blockIdx.x;
    const int tid = threadIdx.x;
    const int r = tid >> 6, o = tid & 63;
    int lo = 0, hi = NN;
    while (lo < hi) { int m = (lo + hi) >> 1; if (batch[m] < gidx) lo = m + 1; else hi = m; }
    const int beg = lo;
    hi = NN;
    while (lo < hi) { int m = (lo + hi) >> 1; if (batch[m] < gidx + 1) lo = m + 1; else hi = m; }
    const int end = lo;
    float acc = 0.f;
    for (int n = beg + r; n < end; n += 4) acc += h[(size_t)n * 64 + o];
    part[r * 64 + o] = acc;
    __syncthreads();
    if (tid < 64) {
        const int cnt = end - beg;
        const float inv = (cnt > 0) ? 1.f / (float)cnt : 1.f;
        hrow[tid] = (part[tid] + part[64 + tid] + part[128 + tid] + part[192 + tid]) * inv;
    }
    __syncthreads();
    if (tid < 64) {
        float s = b1[tid];
#pragma unroll
        for (int k = 0; k < 64; ++k) s += hrow[k] * w1[k * 64 + tid];
        s = silu_f(s);
        float v = s * w2[tid];
#pragma unroll
        for (int d = 32; d > 0; d >>= 1) v += __shfl_down(v, d);
        if (tid == 0) out[gidx] = v + b2[0];
    }
}

extern "C" void kernel_launch(void* const* d_in, const int* in_sizes, int n_in,
                              void* d_out, int out_size, void* d_ws, size_t ws_size,
                              hipStream_t stream) {
    const float* x     = (const float*)d_in[0];
    const float* ea    = (const float*)d_in[1];
    const int*   ei    = (const int*)  d_in[2];
    const int*   batch = (const int*)  d_in[3];
    const float* pw    = (const float*)d_in[4];
    const float* pb    = (const float*)d_in[5];
    const float* ew1   = (const float*)d_in[6];
    const float* eb1   = (const float*)d_in[7];
    const float* ew2   = (const float*)d_in[8];
    const float* eb2   = (const float*)d_in[9];
    const float* rw    = (const float*)d_in[10];
    const float* cb    = (const float*)d_in[11];
    const float* hw1   = (const float*)d_in[12];
    const float* hb1   = (const float*)d_in[13];
    const float* hw2   = (const float*)d_in[14];
    const float* hb2   = (const float*)d_in[15];
    float* out = (float*)d_out;

    float* ws = (float*)d_ws;
    size_t off = 0;
    auto alloc = [&](size_t n) {
        float* p = ws + off;
        off += (n + 63) & ~(size_t)63;
        return p;
    };
    float* hA   = alloc((size_t)NN * 64);
    float* hBuf = alloc((size_t)NN * 64);
    float* gbuf = alloc((size_t)NE * 64);
    float* msg  = alloc((size_t)NE * 64);
    float* Cbuf = alloc((size_t)NN * 64);
    float* invd = alloc(NN);
    int* off_s = (int*)alloc(NN + 1);
    int* off_d = (int*)alloc(NN + 1);
    int* cnt_s = (int*)alloc(NN);
    int* cnt_d = (int*)alloc(NN);
    int* cur_s = (int*)alloc(NN);
    int* cur_d = (int*)alloc(NN);
    int* eid_s = (int*)alloc(NE);
    int* eid_d = (int*)alloc(NE);
    float* Bch = alloc((size_t)((NCH + MT - 1) / MT) * MT * 4096);   // 41 MB

    hipMemsetAsync(cnt_s, 0, NN * sizeof(int), stream);
    hipMemsetAsync(cnt_d, 0, NN * sizeof(int), stream);

    k_hist<<<dim3((NE + 255) / 256), dim3(256), 0, stream>>>(ei, cnt_s, cnt_d);
    k_invdeg<<<dim3((NN + 255) / 256), dim3(256), 0, stream>>>(cnt_d, invd);
    k_scan<<<dim3(1), dim3(1024), 0, stream>>>(cnt_s, off_s, cur_s);
    k_scan<<<dim3(1), dim3(1024), 0, stream>>>(cnt_d, off_d, cur_d);
    k_fill<<<dim3((NE + 255) / 256), dim3(256), 0, stream>>>(ei, off_s, cur_s, eid_s);
    k_fill<<<dim3((NE + 255) / 256), dim3(256), 0, stream>>>(ei + NE, off_d, cur_d, eid_d);

    // h = x @ proj_w + proj_b
    k_rowmm<64, false, true><<<dim3(NN / 4), dim3(256), 0, stream>>>(x, pw, pb, hA, NN);

    float* hcur = hA;
    float* hnxt = hBuf;
    for (int l = 0; l < NLAYERS; l++) {
        // g = silu(edge_attr @ w1 + b1)
        k_rowmm<16, true, true><<<dim3(NE / 4), dim3(256), 0, stream>>>(
            ea, ew1 + (size_t)l * EDIM * 64, eb1 + (size_t)l * 64, gbuf, NE);
        // C = h @ b2(reshaped 64x64)
        k_rowmm<64, false, false><<<dim3(NN / 4), dim3(256), 0, stream>>>(
            hcur, eb2 + (size_t)l * 4096, nullptr, Cbuf, NN);
        for (int n0 = 0; n0 < NN; n0 += NCH) {
            const int n1 = (n0 + NCH < NN) ? n0 + NCH : NN;
            const int nCnt = n1 - n0;
            k_bgemm<<<dim3((nCnt + MT - 1) / MT, 8), dim3(256), 0, stream>>>(
                hcur, ew2 + (size_t)l * 64 * 4096, Bch, n0, n1);
            k_edge2<<<dim3((nCnt + 3) / 4), dim3(256), 0, stream>>>(
                gbuf, Bch, Cbuf, off_s, eid_s, msg, n0, nCnt);
        }
        k_aggfin<<<dim3(NN / 4), dim3(256), 0, stream>>>(
            hcur, msg, off_d, eid_d, invd, rw + (size_t)l * 64 * 64,
            cb + (size_t)l * 64, hnxt);
        float* t = hcur; hcur = hnxt; hnxt = t;
    }

    k_poolhead<<<dim3(NGRAPH), dim3(256), 0, stream>>>(
        hcur, batch, hw1, hb1, hw2, hb2, out);
}

// Round 11
// 561.752 us; speedup vs baseline: 1.1727x; 1.1727x over previous
//
#include <hip/hip_runtime.h>
#include <math.h>

#define NN 10000
#define NE 40000
#define NGRAPH 64
#define HID 64
#define EDIM 16
#define NLAYERS 3
#define MT 32               // node tile of k_bgemm

__device__ __forceinline__ float silu_f(float x) { return x / (1.f + expf(-x)); }

// ---------------- small row GEMM: out[M][64] = act(A[M][K] @ W[K][64] + bias) ----
template<int K, bool DO_SILU, bool HAS_BIAS>
__global__ __launch_bounds__(256)
void k_rowmm(const float* __restrict__ A, const float* __restrict__ W,
             const float* __restrict__ bias, float* __restrict__ out, int M) {
    __shared__ float Ws[K * 64];
    __shared__ float As[4 * K];
    const int tid = threadIdx.x;
    for (int idx = tid; idx < K * 64; idx += 256) Ws[idx] = W[idx];
    const int r0 = blockIdx.x * 4;
    for (int idx = tid; idx < 4 * K; idx += 256) {
        int r = r0 + idx / K;
        As[idx] = (r < M) ? A[(size_t)r * K + (idx % K)] : 0.f;
    }
    __syncthreads();
    const int rr = tid >> 6, c = tid & 63;
    const int r = r0 + rr;
    if (r >= M) return;
    float s = HAS_BIAS ? bias[c] : 0.f;
#pragma unroll
    for (int k = 0; k < K; k++) s += As[rr * K + k] * Ws[k * 64 + c];
    if (DO_SILU) s = silu_f(s);
    out[(size_t)r * 64 + c] = s;
}

// ---------------- degree histograms (src + dst) ----------------
__global__ void k_hist(const int* __restrict__ ei, int* __restrict__ cnt_s,
                       int* __restrict__ cnt_d) {
    int e = blockIdx.x * 256 + threadIdx.x;
    if (e >= NE) return;
    atomicAdd(&cnt_s[ei[e]], 1);
    atomicAdd(&cnt_d[ei[NE + e]], 1);
}

__global__ void k_invdeg(const int* __restrict__ cnt_d, float* __restrict__ invd) {
    int n = blockIdx.x * 256 + threadIdx.x;
    if (n < NN) {
        int d = cnt_d[n];
        invd[n] = (d > 0) ? 1.f / (float)d : 0.f;
    }
}

// ---------------- single-block exclusive scan over NN counts ----------------
__global__ __launch_bounds__(1024)
void k_scan(const int* __restrict__ cnt, int* __restrict__ off, int* __restrict__ cur) {
    __shared__ int part[1024];
    const int t = threadIdx.x;
    const int CH = (NN + 1023) / 1024;  // 10
    const int base0 = t * CH;
    int s = 0;
    for (int i = 0; i < CH; i++) {
        int idx = base0 + i;
        if (idx < NN) s += cnt[idx];
    }
    part[t] = s;
    __syncthreads();
    for (int d = 1; d < 1024; d <<= 1) {
        int v = (t >= d) ? part[t - d] : 0;
        __syncthreads();
        part[t] += v;
        __syncthreads();
    }
    int run = (t == 0) ? 0 : part[t - 1];
    for (int i = 0; i < CH; i++) {
        int idx = base0 + i;
        if (idx < NN) {
            off[idx] = run;
            run += cnt[idx];
            cur[idx] = 0;
        }
    }
    if (t == 1023) off[NN] = run;
}

__global__ void k_fill(const int* __restrict__ keys, const int* __restrict__ off,
                       int* __restrict__ cur, int* __restrict__ eid) {
    int e = blockIdx.x * 256 + threadIdx.x;
    if (e >= NE) return;
    int s = keys[e];
    int p = atomicAdd(&cur[s], 1);
    eid[off[s] + p] = e;
}

// ---------------- B-chunk GEMM v4: MTILE=32 + 4-deep w2 prefetch ----------------
// grid (ceil(n/32), 16); block 256 = 4 waves; thread (k = kb*4 + wave, o = lane).
// The w2 loads for iteration group i4+1 are issued before the 128 FMAs of group
// i4 (~256 VALU cyc) -> L2 latency hidden (v3 stalled: VGPR=40, JIT loads).
__global__ __launch_bounds__(256, 4)
void k_bgemm(const float* __restrict__ h, const float* __restrict__ w2,
             float* __restrict__ B, int n0, int n1) {
    __shared__ float h_s[64 * 40];   // [i][j], stride 40 (float4-aligned)
    const int tid = threadIdx.x;
    const int mb = blockIdx.x, kb = blockIdx.y;
    const int row0 = n0 + mb * MT;
#pragma unroll
    for (int idx = tid; idx < 64 * MT; idx += 256) {
        const int j = idx >> 6, i = idx & 63;       // coalesced global read
        const int row = row0 + j;
        h_s[i * 40 + j] = (row < n1) ? h[(size_t)row * 64 + i] : 0.f;
    }
    __syncthreads();

    const int k = kb * 4 + (tid >> 6);
    const int o = tid & 63;
    const float* wp = w2 + (size_t)k * 4096 + o;    // dense 256B wave loads
    float acc[MT];
#pragma unroll
    for (int j = 0; j < MT; ++j) acc[j] = 0.f;

    float wv0 = wp[0 * 64], wv1 = wp[1 * 64], wv2 = wp[2 * 64], wv3 = wp[3 * 64];
    for (int i4 = 0; i4 < 16; ++i4) {
        const int ib = ((i4 + 1) & 15) * 4;         // wraps once at tail (harmless)
        const float wn0 = wp[(ib + 0) * 64];
        const float wn1 = wp[(ib + 1) * 64];
        const float wn2 = wp[(ib + 2) * 64];
        const float wn3 = wp[(ib + 3) * 64];
#pragma unroll
        for (int p = 0; p < 4; ++p) {
            const float w = (p == 0) ? wv0 : (p == 1) ? wv1 : (p == 2) ? wv2 : wv3;
            const float* hr = h_s + (i4 * 4 + p) * 40;
#pragma unroll
            for (int j8 = 0; j8 < 8; ++j8) {        // LDS broadcast float4 reads
                const float4 hv = *(const float4*)(hr + j8 * 4);
                acc[j8 * 4 + 0] += w * hv.x;
                acc[j8 * 4 + 1] += w * hv.y;
                acc[j8 * 4 + 2] += w * hv.z;
                acc[j8 * 4 + 3] += w * hv.w;
            }
        }
        wv0 = wn0; wv1 = wn1; wv2 = wn2; wv3 = wn3;
    }
    float* Bp = B + ((size_t)mb * MT) * 4096 + k * 64 + o;   // dense 256B stores
#pragma unroll
    for (int j = 0; j < MT; ++j) Bp[(size_t)j * 4096] = acc[j];
}

// ---------------- src-grouped edge kernel: wave per source node ----------------
__global__ __launch_bounds__(256, 1)
void k_edge2(const float* __restrict__ g, const float* __restrict__ B,
             const float* __restrict__ Cbuf, const int* __restrict__ off_s,
             const int* __restrict__ eid_s, float* __restrict__ msg,
             int n0, int nCnt) {
    const int widx = blockIdx.x * 4 + (threadIdx.x >> 6);
    if (widx >= nCnt) return;
    const int n = n0 + widx;
    const int o = threadIdx.x & 63;
    const int p0 = off_s[n], p1 = off_s[n + 1];
    if (p0 == p1) return;                       // no out-edges: skip B load
    const float* Brow = B + (size_t)widx * 4096 + o;
    float b[64];
#pragma unroll
    for (int k = 0; k < 64; ++k) b[k] = Brow[k * 64];   // dense 256B wave loads
    const float cv = Cbuf[(size_t)n * 64 + o];
    for (int p = p0; p < p1; ++p) {
        const int e = __builtin_amdgcn_readfirstlane(eid_s[p]);
        const float* grow = g + (size_t)e * 64;          // uniform -> scalar loads
        float m = cv;
#pragma unroll
        for (int k = 0; k < 64; ++k) m += grow[k] * b[k];
        msg[(size_t)e * 64 + o] = m;
    }
}

// ---------------- gather by dst + root GEMM + silu ----------------
__global__ __launch_bounds__(256)
void k_aggfin(const float* __restrict__ h, const float* __restrict__ msg,
              const int* __restrict__ off2, const int* __restrict__ eid2,
              const float* __restrict__ invd, const float* __restrict__ rw,
              const float* __restrict__ cb, float* __restrict__ hout) {
    __shared__ float Ws[64 * 64];
    __shared__ float As[4 * 64];
    __shared__ int eoff[5];
    const int tid = threadIdx.x;
    for (int idx = tid; idx < 64 * 64; idx += 256) Ws[idx] = rw[idx];
    const int r0 = blockIdx.x * 4;
    As[tid] = h[(size_t)r0 * 64 + tid];
    if (tid < 5) eoff[tid] = off2[r0 + tid];
    __syncthreads();
    const int rr = tid >> 6, c = tid & 63;
    const int r = r0 + rr;
    float a = 0.f;
    for (int p = eoff[rr]; p < eoff[rr + 1]; ++p) {
        const int e = eid2[p];
        a += msg[(size_t)e * 64 + c];
    }
    float s = cb[c] + a * invd[r];
#pragma unroll
    for (int k = 0; k < 64; k++) s += As[rr * 64 + k] * Ws[k * 64 + c];
    hout[(size_t)r * 64 + c] = silu_f(s);
}

// ---------------- fused mean-pool + head MLP (no atomics) ----------------
__global__ __launch_bounds__(256)
void k_poolhead(const float* __restrict__ h, const int* __restrict__ batch,
                const float* __restrict__ w1, const float* __restrict__ b1,
                const float* __restrict__ w2, const float* __restrict__ b2,
                float* __restrict__ out) {
    __shared__ float part[4 * 64];
    __shared__ float hrow[64];
    const int gidx = blockIdx.x;
    const int tid = threadIdx.x;
    const int r = tid >> 6, o = tid & 63;
    int lo = 0, hi = NN;
    while (lo < hi) { int m = (lo + hi) >> 1; if (batch[m] < gidx) lo = m + 1; else hi = m; }
    const int beg = lo;
    hi = NN;
    while (lo < hi) { int m = (lo + hi) >> 1; if (batch[m] < gidx + 1) lo = m + 1; else hi = m; }
    const int end = lo;
    float acc = 0.f;
    for (int n = beg + r; n < end; n += 4) acc += h[(size_t)n * 64 + o];
    part[r * 64 + o] = acc;
    __syncthreads();
    if (tid < 64) {
        const int cnt = end - beg;
        const float inv = (cnt > 0) ? 1.f / (float)cnt : 1.f;
        hrow[tid] = (part[tid] + part[64 + tid] + part[128 + tid] + part[192 + tid]) * inv;
    }
    __syncthreads();
    if (tid < 64) {
        float s = b1[tid];
#pragma unroll
        for (int k = 0; k < 64; ++k) s += hrow[k] * w1[k * 64 + tid];
        s = silu_f(s);
        float v = s * w2[tid];
#pragma unroll
        for (int d = 32; d > 0; d >>= 1) v += __shfl_down(v, d);
        if (tid == 0) out[gidx] = v + b2[0];
    }
}

extern "C" void kernel_launch(void* const* d_in, const int* in_sizes, int n_in,
                              void* d_out, int out_size, void* d_ws, size_t ws_size,
                              hipStream_t stream) {
    const float* x     = (const float*)d_in[0];
    const float* ea    = (const float*)d_in[1];
    const int*   ei    = (const int*)  d_in[2];
    const int*   batch = (const int*)  d_in[3];
    const float* pw    = (const float*)d_in[4];
    const float* pb    = (const float*)d_in[5];
    const float* ew1   = (const float*)d_in[6];
    const float* eb1   = (const float*)d_in[7];
    const float* ew2   = (const float*)d_in[8];
    const float* eb2   = (const float*)d_in[9];
    const float* rw    = (const float*)d_in[10];
    const float* cb    = (const float*)d_in[11];
    const float* hw1   = (const float*)d_in[12];
    const float* hb1   = (const float*)d_in[13];
    const float* hw2   = (const float*)d_in[14];
    const float* hb2   = (const float*)d_in[15];
    float* out = (float*)d_out;

    float* ws = (float*)d_ws;
    size_t off = 0;
    auto alloc = [&](size_t n) {
        float* p = ws + off;
        off += (n + 63) & ~(size_t)63;
        return p;
    };
    float* hA   = alloc((size_t)NN * 64);
    float* hBuf = alloc((size_t)NN * 64);
    float* gbuf = alloc((size_t)NE * 64);
    float* msg  = alloc((size_t)NE * 64);
    float* Cbuf = alloc((size_t)NN * 64);
    float* invd = alloc(NN);
    int* off_s = (int*)alloc(NN + 1);
    int* off_d = (int*)alloc(NN + 1);
    int* cnt_s = (int*)alloc(NN);
    int* cnt_d = (int*)alloc(NN);
    int* cur_s = (int*)alloc(NN);
    int* cur_d = (int*)alloc(NN);
    int* eid_s = (int*)alloc(NE);
    int* eid_d = (int*)alloc(NE);

    // choose chunking for B by available workspace (deterministic: ws_size fixed)
    const size_t fixedFloats = off;
    int nch = 2496;
    {
        auto fits = [&](int rows) {
            size_t padRows = (size_t)((rows + MT - 1) / MT) * MT;
            return (fixedFloats + padRows * 4096 + 64) * sizeof(float) <= ws_size;
        };
        if (fits(10000)) nch = 10000;
        else if (fits(5000)) nch = 5000;
    }
    float* Bch = alloc((size_t)((nch + MT - 1) / MT) * MT * 4096);

    hipMemsetAsync(cnt_s, 0, NN * sizeof(int), stream);
    hipMemsetAsync(cnt_d, 0, NN * sizeof(int), stream);

    k_hist<<<dim3((NE + 255) / 256), dim3(256), 0, stream>>>(ei, cnt_s, cnt_d);
    k_invdeg<<<dim3((NN + 255) / 256), dim3(256), 0, stream>>>(cnt_d, invd);
    k_scan<<<dim3(1), dim3(1024), 0, stream>>>(cnt_s, off_s, cur_s);
    k_scan<<<dim3(1), dim3(1024), 0, stream>>>(cnt_d, off_d, cur_d);
    k_fill<<<dim3((NE + 255) / 256), dim3(256), 0, stream>>>(ei, off_s, cur_s, eid_s);
    k_fill<<<dim3((NE + 255) / 256), dim3(256), 0, stream>>>(ei + NE, off_d, cur_d, eid_d);

    // h = x @ proj_w + proj_b
    k_rowmm<64, false, true><<<dim3(NN / 4), dim3(256), 0, stream>>>(x, pw, pb, hA, NN);

    float* hcur = hA;
    float* hnxt = hBuf;
    for (int l = 0; l < NLAYERS; l++) {
        // g = silu(edge_attr @ w1 + b1)
        k_rowmm<16, true, true><<<dim3(NE / 4), dim3(256), 0, stream>>>(
            ea, ew1 + (size_t)l * EDIM * 64, eb1 + (size_t)l * 64, gbuf, NE);
        // C = h @ b2(reshaped 64x64)
        k_rowmm<64, false, false><<<dim3(NN / 4), dim3(256), 0, stream>>>(
            hcur, eb2 + (size_t)l * 4096, nullptr, Cbuf, NN);
        for (int n0 = 0; n0 < NN; n0 += nch) {
            const int n1 = (n0 + nch < NN) ? n0 + nch : NN;
            const int nCnt = n1 - n0;
            k_bgemm<<<dim3((nCnt + MT - 1) / MT, 16), dim3(256), 0, stream>>>(
                hcur, ew2 + (size_t)l * 64 * 4096, Bch, n0, n1);
            k_edge2<<<dim3((nCnt + 3) / 4), dim3(256), 0, stream>>>(
                gbuf, Bch, Cbuf, off_s, eid_s, msg, n0, nCnt);
        }
        k_aggfin<<<dim3(NN / 4), dim3(256), 0, stream>>>(
            hcur, msg, off_d, eid_d, invd, rw + (size_t)l * 64 * 64,
            cb + (size_t)l * 64, hnxt);
        float* t = hcur; hcur = hnxt; hnxt = t;
    }

    k_poolhead<<<dim3(NGRAPH), dim3(256), 0, stream>>>(
        hcur, batch, hw1, hb1, hw2, hb2, out);
}

// Round 12
// 520.323 us; speedup vs baseline: 1.2661x; 1.0796x over previous
//
#include <hip/hip_runtime.h>
#include <math.h>

#define NN 10000
#define NE 40000
#define NGRAPH 64
#define HID 64
#define EDIM 16
#define NLAYERS 3
#define MT 32               // node tile of k_bgemm
#define HSTR 44             // h_s stride: float4-aligned (176B), 8-way banks

__device__ __forceinline__ float silu_f(float x) { return x / (1.f + expf(-x)); }

// ---------------- small row GEMM: out[M][64] = act(A[M][K] @ W[K][64] + bias) ----
template<int K, bool DO_SILU, bool HAS_BIAS>
__global__ __launch_bounds__(256)
void k_rowmm(const float* __restrict__ A, const float* __restrict__ W,
             const float* __restrict__ bias, float* __restrict__ out, int M) {
    __shared__ float Ws[K * 64];
    __shared__ float As[4 * K];
    const int tid = threadIdx.x;
    for (int idx = tid; idx < K * 64; idx += 256) Ws[idx] = W[idx];
    const int r0 = blockIdx.x * 4;
    for (int idx = tid; idx < 4 * K; idx += 256) {
        int r = r0 + idx / K;
        As[idx] = (r < M) ? A[(size_t)r * K + (idx % K)] : 0.f;
    }
    __syncthreads();
    const int rr = tid >> 6, c = tid & 63;
    const int r = r0 + rr;
    if (r >= M) return;
    float s = HAS_BIAS ? bias[c] : 0.f;
#pragma unroll
    for (int k = 0; k < K; k++) s += As[rr * K + k] * Ws[k * 64 + c];
    if (DO_SILU) s = silu_f(s);
    out[(size_t)r * 64 + c] = s;
}

// ---------------- batched edge-MLP for ALL layers: g3[l] = silu(ea@w1[l]+b1[l]) ----
__global__ __launch_bounds__(256)
void k_gmm3(const float* __restrict__ ea, const float* __restrict__ ew1,
            const float* __restrict__ eb1, float* __restrict__ g3) {
    const int l = blockIdx.y;
    const float* W = ew1 + (size_t)l * EDIM * 64;
    const float* bias = eb1 + (size_t)l * 64;
    float* out = g3 + (size_t)l * NE * 64;
    __shared__ float Ws[EDIM * 64];
    __shared__ float As[4 * EDIM];
    const int tid = threadIdx.x;
    for (int idx = tid; idx < EDIM * 64; idx += 256) Ws[idx] = W[idx];
    const int r0 = blockIdx.x * 4;
    if (tid < 4 * EDIM) As[tid] = ea[(size_t)r0 * EDIM + tid];
    __syncthreads();
    const int rr = tid >> 6, c = tid & 63;
    float s = bias[c];
#pragma unroll
    for (int k = 0; k < EDIM; k++) s += As[rr * EDIM + k] * Ws[k * 64 + c];
    out[(size_t)(r0 + rr) * 64 + c] = silu_f(s);
}

// ---------------- degree histograms (src + dst) ----------------
__global__ void k_hist(const int* __restrict__ ei, int* __restrict__ cnt_s,
                       int* __restrict__ cnt_d) {
    int e = blockIdx.x * 256 + threadIdx.x;
    if (e >= NE) return;
    atomicAdd(&cnt_s[ei[e]], 1);
    atomicAdd(&cnt_d[ei[NE + e]], 1);
}

// ---------------- single-block: both exclusive scans + invdeg ----------------
__global__ __launch_bounds__(1024)
void k_scan2(const int* __restrict__ cnt_s, const int* __restrict__ cnt_d,
             int* __restrict__ off_s, int* __restrict__ off_d,
             int* __restrict__ cur_s, int* __restrict__ cur_d,
             float* __restrict__ invd) {
    __shared__ int part[1024];
    const int t = threadIdx.x;
    const int CH = (NN + 1023) / 1024;  // 10
    const int base0 = t * CH;
#pragma unroll
    for (int pass = 0; pass < 2; ++pass) {
        const int* cnt = pass ? cnt_d : cnt_s;
        int* off = pass ? off_d : off_s;
        int* cur = pass ? cur_d : cur_s;
        int s = 0;
        for (int i = 0; i < CH; i++) {
            int idx = base0 + i;
            if (idx < NN) s += cnt[idx];
        }
        part[t] = s;
        __syncthreads();
        for (int d = 1; d < 1024; d <<= 1) {
            int v = (t >= d) ? part[t - d] : 0;
            __syncthreads();
            part[t] += v;
            __syncthreads();
        }
        int run = (t == 0) ? 0 : part[t - 1];
        for (int i = 0; i < CH; i++) {
            int idx = base0 + i;
            if (idx < NN) {
                off[idx] = run;
                int c = cnt[idx];
                if (pass) invd[idx] = (c > 0) ? 1.f / (float)c : 0.f;
                run += c;
                cur[idx] = 0;
            }
        }
        if (t == 1023) off[NN] = run;
        __syncthreads();
    }
}

__global__ void k_fill(const int* __restrict__ keys, const int* __restrict__ off,
                       int* __restrict__ cur, int* __restrict__ eid) {
    int e = blockIdx.x * 256 + threadIdx.x;
    if (e >= NE) return;
    int s = keys[e];
    int p = atomicAdd(&cur[s], 1);
    eid[off[s] + p] = e;
}

// ---------------- B-chunk GEMM v5: 512thr, 8 waves, fused C, stride-44 LDS ----
// grid (ceil(n/32), 8); wave -> k = kb*8 + wave, lane -> o. kb==0 also computes
// C[n,o] = sum_i h[n,i]*b2[i*64+o] from the staged h_s (removes rowmm_C dispatch).
__global__ __launch_bounds__(512, 4)
void k_bgemm(const float* __restrict__ h, const float* __restrict__ w2,
             const float* __restrict__ b2, float* __restrict__ B,
             float* __restrict__ C, int n0, int n1) {
    __shared__ float h_s[64 * HSTR];
    const int tid = threadIdx.x;
    const int mb = blockIdx.x, kb = blockIdx.y;
    const int row0 = n0 + mb * MT;
#pragma unroll
    for (int idx = tid; idx < 64 * MT; idx += 512) {
        const int j = idx >> 6, i = idx & 63;       // coalesced global read
        const int row = row0 + j;
        h_s[i * HSTR + j] = (row < n1) ? h[(size_t)row * 64 + i] : 0.f;
    }
    __syncthreads();

    const int k = kb * 8 + (tid >> 6);
    const int o = tid & 63;
    const float* wp = w2 + (size_t)k * 4096 + o;    // dense 256B wave loads
    float acc[MT];
#pragma unroll
    for (int j = 0; j < MT; ++j) acc[j] = 0.f;

    float wv0 = wp[0 * 64], wv1 = wp[1 * 64], wv2 = wp[2 * 64], wv3 = wp[3 * 64];
    for (int i4 = 0; i4 < 16; ++i4) {
        const int ib = ((i4 + 1) & 15) * 4;
        const float wn0 = wp[(ib + 0) * 64];
        const float wn1 = wp[(ib + 1) * 64];
        const float wn2 = wp[(ib + 2) * 64];
        const float wn3 = wp[(ib + 3) * 64];
#pragma unroll
        for (int p = 0; p < 4; ++p) {
            const float w = (p == 0) ? wv0 : (p == 1) ? wv1 : (p == 2) ? wv2 : wv3;
            const float* hr = h_s + (i4 * 4 + p) * HSTR;
#pragma unroll
            for (int j8 = 0; j8 < 8; ++j8) {        // LDS broadcast float4 reads
                const float4 hv = *(const float4*)(hr + j8 * 4);
                acc[j8 * 4 + 0] += w * hv.x;
                acc[j8 * 4 + 1] += w * hv.y;
                acc[j8 * 4 + 2] += w * hv.z;
                acc[j8 * 4 + 3] += w * hv.w;
            }
        }
        wv0 = wn0; wv1 = wn1; wv2 = wn2; wv3 = wn3;
    }
    float* Bp = B + ((size_t)mb * MT) * 4096 + k * 64 + o;   // dense 256B stores
#pragma unroll
    for (int j = 0; j < MT; ++j) Bp[(size_t)j * 4096] = acc[j];

    if (kb == 0) {   // ---- fused C for this block's 32 nodes (4 per wave) ----
        const int jj0 = (tid >> 6) * 4;
        float c0 = 0.f, c1 = 0.f, c2 = 0.f, c3 = 0.f;
        const float* bp = b2 + o;
#pragma unroll 8
        for (int i = 0; i < 64; ++i) {
            const float bv = bp[i * 64];            // dense 256B wave loads
            const float* hr = h_s + i * HSTR + jj0;
            c0 += bv * hr[0]; c1 += bv * hr[1];
            c2 += bv * hr[2]; c3 += bv * hr[3];
        }
        const int rb = row0 + jj0;
        if (rb + 0 < n1) C[(size_t)(rb + 0) * 64 + o] = c0;
        if (rb + 1 < n1) C[(size_t)(rb + 1) * 64 + o] = c1;
        if (rb + 2 < n1) C[(size_t)(rb + 2) * 64 + o] = c2;
        if (rb + 3 < n1) C[(size_t)(rb + 3) * 64 + o] = c3;
    }
}

// ---------------- src-grouped edge kernel: wave per source node ----------------
__global__ __launch_bounds__(256, 1)
void k_edge2(const float* __restrict__ g, const float* __restrict__ B,
             const float* __restrict__ Cbuf, const int* __restrict__ off_s,
             const int* __restrict__ eid_s, float* __restrict__ msg,
             int n0, int nCnt) {
    const int widx = blockIdx.x * 4 + (threadIdx.x >> 6);
    if (widx >= nCnt) return;
    const int n = n0 + widx;
    const int o = threadIdx.x & 63;
    const int p0 = off_s[n], p1 = off_s[n + 1];
    if (p0 == p1) return;                       // no out-edges: skip B load
    const float* Brow = B + (size_t)widx * 4096 + o;
    float b[64];
#pragma unroll
    for (int k = 0; k < 64; ++k) b[k] = Brow[k * 64];   // dense 256B wave loads
    const float cv = Cbuf[(size_t)n * 64 + o];
    for (int p = p0; p < p1; ++p) {
        const int e = __builtin_amdgcn_readfirstlane(eid_s[p]);
        const float* grow = g + (size_t)e * 64;          // uniform -> scalar loads
        float m = cv;
#pragma unroll
        for (int k = 0; k < 64; ++k) m += grow[k] * b[k];
        msg[(size_t)e * 64 + o] = m;
    }
}

// ---------------- gather by dst + root GEMM + silu (8 rows/block) ----------------
__global__ __launch_bounds__(256)
void k_aggfin(const float* __restrict__ h, const float* __restrict__ msg,
              const int* __restrict__ off2, const int* __restrict__ eid2,
              const float* __restrict__ invd, const float* __restrict__ rw,
              const float* __restrict__ cb, float* __restrict__ hout) {
    __shared__ float Ws[64 * 64];
    __shared__ float As[8 * 64];
    __shared__ int eoff[9];
    const int tid = threadIdx.x;
    for (int idx = tid; idx < 64 * 64; idx += 256) Ws[idx] = rw[idx];
    const int r0 = blockIdx.x * 8;
    for (int idx = tid; idx < 8 * 64; idx += 256) As[idx] = h[(size_t)r0 * 64 + idx];
    if (tid < 9) eoff[tid] = off2[r0 + tid];
    __syncthreads();
    const int rr = tid >> 6, c = tid & 63;
#pragma unroll
    for (int half = 0; half < 2; ++half) {
        const int lr = half * 4 + rr;
        const int r = r0 + lr;
        float a = 0.f;
        for (int p = eoff[lr]; p < eoff[lr + 1]; ++p) {
            a += msg[(size_t)eid2[p] * 64 + c];
        }
        float s = cb[c] + a * invd[r];
        const float* Ar = As + lr * 64;
#pragma unroll
        for (int k = 0; k < 64; k++) s += Ar[k] * Ws[k * 64 + c];
        hout[(size_t)r * 64 + c] = silu_f(s);
    }
}

// ---------------- fused mean-pool + head MLP (no atomics) ----------------
__global__ __launch_bounds__(256)
void k_poolhead(const float* __restrict__ h, const int* __restrict__ batch,
                const float* __restrict__ w1, const float* __restrict__ b1,
                const float* __restrict__ w2, const float* __restrict__ b2,
                float* __restrict__ out) {
    __shared__ float part[4 * 64];
    __shared__ float hrow[64];
    const int gidx = blockIdx.x;
    const int tid = threadIdx.x;
    const int r = tid >> 6, o = tid & 63;
    int lo = 0, hi = NN;
    while (lo < hi) { int m = (lo + hi) >> 1; if (batch[m] < gidx) lo = m + 1; else hi = m; }
    const int beg = lo;
    hi = NN;
    while (lo < hi) { int m = (lo + hi) >> 1; if (batch[m] < gidx + 1) lo = m + 1; else hi = m; }
    const int end = lo;
    float acc = 0.f;
    for (int n = beg + r; n < end; n += 4) acc += h[(size_t)n * 64 + o];
    part[r * 64 + o] = acc;
    __syncthreads();
    if (tid < 64) {
        const int cnt = end - beg;
        const float inv = (cnt > 0) ? 1.f / (float)cnt : 1.f;
        hrow[tid] = (part[tid] + part[64 + tid] + part[128 + tid] + part[192 + tid]) * inv;
    }
    __syncthreads();
    if (tid < 64) {
        float s = b1[tid];
#pragma unroll
        for (int k = 0; k < 64; ++k) s += hrow[k] * w1[k * 64 + tid];
        s = silu_f(s);
        float v = s * w2[tid];
#pragma unroll
        for (int d = 32; d > 0; d >>= 1) v += __shfl_down(v, d);
        if (tid == 0) out[gidx] = v + b2[0];
    }
}

extern "C" void kernel_launch(void* const* d_in, const int* in_sizes, int n_in,
                              void* d_out, int out_size, void* d_ws, size_t ws_size,
                              hipStream_t stream) {
    const float* x     = (const float*)d_in[0];
    const float* ea    = (const float*)d_in[1];
    const int*   ei    = (const int*)  d_in[2];
    const int*   batch = (const int*)  d_in[3];
    const float* pw    = (const float*)d_in[4];
    const float* pb    = (const float*)d_in[5];
    const float* ew1   = (const float*)d_in[6];
    const float* eb1   = (const float*)d_in[7];
    const float* ew2   = (const float*)d_in[8];
    const float* eb2   = (const float*)d_in[9];
    const float* rw    = (const float*)d_in[10];
    const float* cb    = (const float*)d_in[11];
    const float* hw1   = (const float*)d_in[12];
    const float* hb1   = (const float*)d_in[13];
    const float* hw2   = (const float*)d_in[14];
    const float* hb2   = (const float*)d_in[15];
    float* out = (float*)d_out;

    float* ws = (float*)d_ws;
    size_t off = 0;
    auto alloc = [&](size_t n) {
        float* p = ws + off;
        off += (n + 63) & ~(size_t)63;
        return p;
    };
    float* hA   = alloc((size_t)NN * 64);
    float* hBuf = alloc((size_t)NN * 64);
    float* msg  = alloc((size_t)NE * 64);
    float* Cbuf = alloc((size_t)NN * 64);
    float* invd = alloc(NN);
    int* off_s = (int*)alloc(NN + 1);
    int* off_d = (int*)alloc(NN + 1);
    int* cnt_s = (int*)alloc(NN);
    int* cnt_d = (int*)alloc(NN);
    int* cur_s = (int*)alloc(NN);
    int* cur_d = (int*)alloc(NN);
    int* eid_s = (int*)alloc(NE);
    int* eid_d = (int*)alloc(NE);

    // g for all 3 layers (batched) if ws allows; else per-layer reuse of one buffer
    const size_t fixedFloats = off;
    const size_t needG3 = (size_t)3 * NE * 64;
    const size_t padB10k = (size_t)((10000 + MT - 1) / MT) * MT * 4096;
    bool batchG = (fixedFloats + needG3 + padB10k + 128) * sizeof(float) <= ws_size;
    float* gbuf = alloc(batchG ? needG3 : (size_t)NE * 64);

    int nch = 2496;
    {
        auto fits = [&](int rows) {
            size_t padRows = (size_t)((rows + MT - 1) / MT) * MT;
            return (off + padRows * 4096 + 64) * sizeof(float) <= ws_size;
        };
        if (fits(10000)) nch = 10000;
        else if (fits(5000)) nch = 5000;
    }
    float* Bch = alloc((size_t)((nch + MT - 1) / MT) * MT * 4096);

    hipMemsetAsync(cnt_s, 0, NN * sizeof(int), stream);
    hipMemsetAsync(cnt_d, 0, NN * sizeof(int), stream);

    k_hist<<<dim3((NE + 255) / 256), dim3(256), 0, stream>>>(ei, cnt_s, cnt_d);
    k_scan2<<<dim3(1), dim3(1024), 0, stream>>>(cnt_s, cnt_d, off_s, off_d,
                                                cur_s, cur_d, invd);
    k_fill<<<dim3((NE + 255) / 256), dim3(256), 0, stream>>>(ei, off_s, cur_s, eid_s);
    k_fill<<<dim3((NE + 255) / 256), dim3(256), 0, stream>>>(ei + NE, off_d, cur_d, eid_d);

    // h = x @ proj_w + proj_b
    k_rowmm<64, false, true><<<dim3(NN / 4), dim3(256), 0, stream>>>(x, pw, pb, hA, NN);

    // g for all layers in one dispatch
    if (batchG) {
        k_gmm3<<<dim3(NE / 4, 3), dim3(256), 0, stream>>>(ea, ew1, eb1, gbuf);
    }

    float* hcur = hA;
    float* hnxt = hBuf;
    for (int l = 0; l < NLAYERS; l++) {
        float* gl = batchG ? gbuf + (size_t)l * NE * 64 : gbuf;
        if (!batchG) {
            k_rowmm<16, true, true><<<dim3(NE / 4), dim3(256), 0, stream>>>(
                ea, ew1 + (size_t)l * EDIM * 64, eb1 + (size_t)l * 64, gl, NE);
        }
        for (int n0 = 0; n0 < NN; n0 += nch) {
            const int n1 = (n0 + nch < NN) ? n0 + nch : NN;
            const int nCnt = n1 - n0;
            k_bgemm<<<dim3((nCnt + MT - 1) / MT, 8), dim3(512), 0, stream>>>(
                hcur, ew2 + (size_t)l * 64 * 4096, eb2 + (size_t)l * 4096,
                Bch, Cbuf, n0, n1);
            k_edge2<<<dim3((nCnt + 3) / 4), dim3(256), 0, stream>>>(
                gl, Bch, Cbuf, off_s, eid_s, msg, n0, nCnt);
        }
        k_aggfin<<<dim3(NN / 8), dim3(256), 0, stream>>>(
            hcur, msg, off_d, eid_d, invd, rw + (size_t)l * 64 * 64,
            cb + (size_t)l * 64, hnxt);
        float* t = hcur; hcur = hnxt; hnxt = t;
    }

    k_poolhead<<<dim3(NGRAPH), dim3(256), 0, stream>>>(
        hcur, batch, hw1, hb1, hw2, hb2, out);
}

// Round 13
// 398.221 us; speedup vs baseline: 1.6543x; 1.3066x over previous
//
#include <hip/hip_runtime.h>
#include <math.h>

#define NN 10000
#define NE 40000
#define NGRAPH 64
#define HID 64
#define EDIM 16
#define NLAYERS 3

#define NRT 625            // row tiles (16 nodes each): 10000/16 exact
#define NCT 260            // col tiles: 4096 (B) + 64 (C from b2) = 4160/16
#define WFRAG 512          // shorts per fragment-slot (64 lanes x 8)
#define PWL ((size_t)NCT * 2 * 3 * WFRAG)   // packed W shorts per layer

typedef __attribute__((ext_vector_type(8))) short bf8v;
typedef __attribute__((ext_vector_type(4))) float f32x4;

__device__ __forceinline__ float silu_f(float x) { return x / (1.f + expf(-x)); }

__device__ __forceinline__ unsigned short f2bf(float f) {
    unsigned int u = __float_as_uint(f);
    u += 0x7fff + ((u >> 16) & 1);          // round-to-nearest-even
    return (unsigned short)(u >> 16);
}
__device__ __forceinline__ float bf2f(unsigned short s) {
    return __uint_as_float(((unsigned int)s) << 16);
}
__device__ __forceinline__ void split3f(float v, short& a, short& b, short& c) {
    unsigned short u1 = f2bf(v);      float f1 = bf2f(u1);
    unsigned short u2 = f2bf(v - f1); float f2 = bf2f(u2);
    unsigned short u3 = f2bf(v - f1 - f2);
    a = (short)u1; b = (short)u2; c = (short)u3;
}

// ---------------- small row GEMM: out[M][64] = act(A[M][K] @ W[K][64] + bias) ----
template<int K, bool DO_SILU, bool HAS_BIAS>
__global__ __launch_bounds__(256)
void k_rowmm(const float* __restrict__ A, const float* __restrict__ W,
             const float* __restrict__ bias, float* __restrict__ out, int M) {
    __shared__ float Ws[K * 64];
    __shared__ float As[4 * K];
    const int tid = threadIdx.x;
    for (int idx = tid; idx < K * 64; idx += 256) Ws[idx] = W[idx];
    const int r0 = blockIdx.x * 4;
    for (int idx = tid; idx < 4 * K; idx += 256) {
        int r = r0 + idx / K;
        As[idx] = (r < M) ? A[(size_t)r * K + (idx % K)] : 0.f;
    }
    __syncthreads();
    const int rr = tid >> 6, c = tid & 63;
    const int r = r0 + rr;
    if (r >= M) return;
    float s = HAS_BIAS ? bias[c] : 0.f;
#pragma unroll
    for (int k = 0; k < K; k++) s += As[rr * K + k] * Ws[k * 64 + c];
    if (DO_SILU) s = silu_f(s);
    out[(size_t)r * 64 + c] = s;
}

// ---------------- batched edge-MLP for ALL layers ----------------
__global__ __launch_bounds__(256)
void k_gmm3(const float* __restrict__ ea, const float* __restrict__ ew1,
            const float* __restrict__ eb1, float* __restrict__ g3) {
    const int l = blockIdx.y;
    const float* W = ew1 + (size_t)l * EDIM * 64;
    const float* bias = eb1 + (size_t)l * 64;
    float* out = g3 + (size_t)l * NE * 64;
    __shared__ float Ws[EDIM * 64];
    __shared__ float As[4 * EDIM];
    const int tid = threadIdx.x;
    for (int idx = tid; idx < EDIM * 64; idx += 256) Ws[idx] = W[idx];
    const int r0 = blockIdx.x * 4;
    if (tid < 4 * EDIM) As[tid] = ea[(size_t)r0 * EDIM + tid];
    __syncthreads();
    const int rr = tid >> 6, c = tid & 63;
    float s = bias[c];
#pragma unroll
    for (int k = 0; k < EDIM; k++) s += As[rr * EDIM + k] * Ws[k * 64 + c];
    out[(size_t)(r0 + rr) * 64 + c] = silu_f(s);
}

// ---------------- degree histograms (src + dst) ----------------
__global__ void k_hist(const int* __restrict__ ei, int* __restrict__ cnt_s,
                       int* __restrict__ cnt_d) {
    int e = blockIdx.x * 256 + threadIdx.x;
    if (e >= NE) return;
    atomicAdd(&cnt_s[ei[e]], 1);
    atomicAdd(&cnt_d[ei[NE + e]], 1);
}

// ---------------- single-block: both exclusive scans + invdeg ----------------
__global__ __launch_bounds__(1024)
void k_scan2(const int* __restrict__ cnt_s, const int* __restrict__ cnt_d,
             int* __restrict__ off_s, int* __restrict__ off_d,
             int* __restrict__ cur_s, int* __restrict__ cur_d,
             float* __restrict__ invd) {
    __shared__ int part[1024];
    const int t = threadIdx.x;
    const int CH = (NN + 1023) / 1024;  // 10
    const int base0 = t * CH;
#pragma unroll
    for (int pass = 0; pass < 2; ++pass) {
        const int* cnt = pass ? cnt_d : cnt_s;
        int* off = pass ? off_d : off_s;
        int* cur = pass ? cur_d : cur_s;
        int s = 0;
        for (int i = 0; i < CH; i++) {
            int idx = base0 + i;
            if (idx < NN) s += cnt[idx];
        }
        part[t] = s;
        __syncthreads();
        for (int d = 1; d < 1024; d <<= 1) {
            int v = (t >= d) ? part[t - d] : 0;
            __syncthreads();
            part[t] += v;
            __syncthreads();
        }
        int run = (t == 0) ? 0 : part[t - 1];
        for (int i = 0; i < CH; i++) {
            int idx = base0 + i;
            if (idx < NN) {
                off[idx] = run;
                int c = cnt[idx];
                if (pass) invd[idx] = (c > 0) ? 1.f / (float)c : 0.f;
                run += c;
                cur[idx] = 0;
            }
        }
        if (t == 1023) off[NN] = run;
        __syncthreads();
    }
}

__global__ void k_fill(const int* __restrict__ keys, const int* __restrict__ off,
                       int* __restrict__ cur, int* __restrict__ eid) {
    int e = blockIdx.x * 256 + threadIdx.x;
    if (e >= NE) return;
    int s = keys[e];
    int p = atomicAdd(&cur[s], 1);
    eid[off[s] + p] = e;
}

// ---------------- pack w2 (+b2 as cols 4096..4159) into MFMA B-fragments ----------
// Layout: [lay][ct][ks][sp][lane][8] bf16; split3 per element.
// B-frag convention (16x16x32): lane l supplies W[ks*32 + (l>>4)*8 + t][ct*16 + (l&15)].
__global__ __launch_bounds__(128)
void k_packw(const float* __restrict__ ew2, const float* __restrict__ eb2,
             short* __restrict__ pw) {
    const int ct = blockIdx.x;      // 0..259
    const int lay = blockIdx.y;     // 0..2
    const int t = threadIdx.x;
    const int l = t & 63, ks = t >> 6;
    const int col = ct * 16 + (l & 15);
    const int i0 = ks * 32 + ((l >> 4) << 3);
    bf8v v1, v2, v3;
#pragma unroll
    for (int tt = 0; tt < 8; ++tt) {
        const int i = i0 + tt;
        float v;
        if (col < 4096)
            v = ew2[(size_t)lay * 262144 + (size_t)(col >> 6) * 4096 + i * 64 + (col & 63)];
        else
            v = eb2[(size_t)lay * 4096 + i * 64 + (col - 4096)];
        short a, b, c;
        split3f(v, a, b, c);
        v1[tt] = a; v2[tt] = b; v3[tt] = c;
    }
    short* dst = pw + ((((size_t)lay * NCT + ct) * 2 + ks) * 3) * WFRAG + l * 8;
    *reinterpret_cast<bf8v*>(dst)        = v1;
    *reinterpret_cast<bf8v*>(dst + 512)  = v2;
    *reinterpret_cast<bf8v*>(dst + 1024) = v3;
}

// ---------------- pack h into MFMA A-fragments (per layer) ----------------
// A-frag convention: lane l supplies h[rt*16 + (l&15)][ks*32 + (l>>4)*8 + t].
__global__ __launch_bounds__(128)
void k_packh(const float* __restrict__ h, short* __restrict__ ph) {
    const int rt = blockIdx.x;
    const int t = threadIdx.x;
    const int l = t & 63, ks = t >> 6;
    const int row = rt * 16 + (l & 15);
    const int i0 = ks * 32 + ((l >> 4) << 3);
    const float* hp = h + (size_t)row * 64 + i0;
    bf8v v1, v2, v3;
#pragma unroll
    for (int tt = 0; tt < 8; ++tt) {
        short a, b, c;
        split3f(hp[tt], a, b, c);
        v1[tt] = a; v2[tt] = b; v3[tt] = c;
    }
    short* dst = ph + (((size_t)rt * 2 + ks) * 3) * WFRAG + l * 8;
    *reinterpret_cast<bf8v*>(dst)        = v1;
    *reinterpret_cast<bf8v*>(dst + 512)  = v2;
    *reinterpret_cast<bf8v*>(dst + 1024) = v3;
}

// ---------------- B GEMM via MFMA bf16 split-3 (6 product terms) ----------------
// grid (ceil(nCnt/32), 17); block 256 = 4 waves. Block covers 32 nodes x 256 cols;
// wave w covers col-tiles chunk*16 + w*4 .. +4. Cols >=4096 are the fused C (b2).
__global__ __launch_bounds__(256, 4)
void k_bgemm_mfma(const short* __restrict__ ph, const short* __restrict__ pw,
                  float* __restrict__ B, float* __restrict__ C, int n0, int n1) {
    const int lane = threadIdx.x & 63;
    const int wid  = threadIdx.x >> 6;
    const int rtLim = n1 >> 4;
    const int rt0 = (n0 >> 4) + blockIdx.x * 2;

    bf8v A[2][2][3];
    bool ok0 = (rt0 < rtLim), ok1 = (rt0 + 1 < rtLim);
#pragma unroll
    for (int rt2 = 0; rt2 < 2; ++rt2) {
        if (rt2 ? !ok1 : !ok0) continue;
        const int rt = rt0 + rt2;
#pragma unroll
        for (int ks = 0; ks < 2; ++ks)
#pragma unroll
            for (int sp = 0; sp < 3; ++sp)
                A[rt2][ks][sp] = *reinterpret_cast<const bf8v*>(
                    ph + (((size_t)rt * 2 + ks) * 3 + sp) * WFRAG + lane * 8);
    }

    const int ctbase = blockIdx.y * 16 + wid * 4;
#pragma unroll
    for (int cc = 0; cc < 4; ++cc) {
        const int ct = ctbase + cc;
        if (ct >= NCT) continue;                 // wave-uniform
        bf8v Bf[2][3];
#pragma unroll
        for (int ks = 0; ks < 2; ++ks)
#pragma unroll
            for (int sp = 0; sp < 3; ++sp)
                Bf[ks][sp] = *reinterpret_cast<const bf8v*>(
                    pw + (((size_t)ct * 2 + ks) * 3 + sp) * WFRAG + lane * 8);

        f32x4 acc0 = {0.f, 0.f, 0.f, 0.f};
        f32x4 acc1 = {0.f, 0.f, 0.f, 0.f};
#pragma unroll
        for (int ks = 0; ks < 2; ++ks) {
#define TERM(s1, s2) \
            if (ok0) acc0 = __builtin_amdgcn_mfma_f32_16x16x32_bf16(A[0][ks][s1], Bf[ks][s2], acc0, 0, 0, 0); \
            if (ok1) acc1 = __builtin_amdgcn_mfma_f32_16x16x32_bf16(A[1][ks][s1], Bf[ks][s2], acc1, 0, 0, 0);
            TERM(0, 0) TERM(0, 1) TERM(1, 0) TERM(0, 2) TERM(1, 1) TERM(2, 0)
#undef TERM
        }
        // C/D layout (m89-verified): col = lane&15, row = (lane>>4)*4 + reg
        const int c = ct * 16 + (lane & 15);
        const int rof = (lane >> 4) << 2;
#pragma unroll
        for (int rt2 = 0; rt2 < 2; ++rt2) {
            if (rt2 ? !ok1 : !ok0) continue;
            const f32x4 acc = rt2 ? acc1 : acc0;
            const int rb = (rt0 + rt2) * 16 + rof;
            if (c < 4096) {
#pragma unroll
                for (int r = 0; r < 4; ++r)
                    B[((size_t)(rb - n0) + r) * 4096 + c] = acc[r];
            } else {
#pragma unroll
                for (int r = 0; r < 4; ++r)
                    C[(size_t)(rb + r) * 64 + (c - 4096)] = acc[r];
            }
        }
    }
}

// ---------------- src-grouped edge kernel: wave per source node ----------------
__global__ __launch_bounds__(256, 1)
void k_edge2(const float* __restrict__ g, const float* __restrict__ B,
             const float* __restrict__ Cbuf, const int* __restrict__ off_s,
             const int* __restrict__ eid_s, float* __restrict__ msg,
             int n0, int nCnt) {
    const int widx = blockIdx.x * 4 + (threadIdx.x >> 6);
    if (widx >= nCnt) return;
    const int n = n0 + widx;
    const int o = threadIdx.x & 63;
    const int p0 = off_s[n], p1 = off_s[n + 1];
    if (p0 == p1) return;
    const float* Brow = B + (size_t)widx * 4096 + o;
    float b[64];
#pragma unroll
    for (int k = 0; k < 64; ++k) b[k] = Brow[k * 64];
    const float cv = Cbuf[(size_t)n * 64 + o];
    for (int p = p0; p < p1; ++p) {
        const int e = __builtin_amdgcn_readfirstlane(eid_s[p]);
        const float* grow = g + (size_t)e * 64;
        float m = cv;
#pragma unroll
        for (int k = 0; k < 64; ++k) m += grow[k] * b[k];
        msg[(size_t)e * 64 + o] = m;
    }
}

// ---------------- gather by dst + root GEMM + silu (8 rows/block) ----------------
__global__ __launch_bounds__(256)
void k_aggfin(const float* __restrict__ h, const float* __restrict__ msg,
              const int* __restrict__ off2, const int* __restrict__ eid2,
              const float* __restrict__ invd, const float* __restrict__ rw,
              const float* __restrict__ cb, float* __restrict__ hout) {
    __shared__ float Ws[64 * 64];
    __shared__ float As[8 * 64];
    __shared__ int eoff[9];
    const int tid = threadIdx.x;
    for (int idx = tid; idx < 64 * 64; idx += 256) Ws[idx] = rw[idx];
    const int r0 = blockIdx.x * 8;
    for (int idx = tid; idx < 8 * 64; idx += 256) As[idx] = h[(size_t)r0 * 64 + idx];
    if (tid < 9) eoff[tid] = off2[r0 + tid];
    __syncthreads();
    const int rr = tid >> 6, c = tid & 63;
#pragma unroll
    for (int half = 0; half < 2; ++half) {
        const int lr = half * 4 + rr;
        const int r = r0 + lr;
        float a = 0.f;
        for (int p = eoff[lr]; p < eoff[lr + 1]; ++p) {
            a += msg[(size_t)eid2[p] * 64 + c];
        }
        float s = cb[c] + a * invd[r];
        const float* Ar = As + lr * 64;
#pragma unroll
        for (int k = 0; k < 64; k++) s += Ar[k] * Ws[k * 64 + c];
        hout[(size_t)r * 64 + c] = silu_f(s);
    }
}

// ---------------- fused mean-pool + head MLP (no atomics) ----------------
__global__ __launch_bounds__(256)
void k_poolhead(const float* __restrict__ h, const int* __restrict__ batch,
                const float* __restrict__ w1, const float* __restrict__ b1,
                const float* __restrict__ w2, const float* __restrict__ b2,
                float* __restrict__ out) {
    __shared__ float part[4 * 64];
    __shared__ float hrow[64];
    const int gidx = blockIdx.x;
    const int tid = threadIdx.x;
    const int r = tid >> 6, o = tid & 63;
    int lo = 0, hi = NN;
    while (lo < hi) { int m = (lo + hi) >> 1; if (batch[m] < gidx) lo = m + 1; else hi = m; }
    const int beg = lo;
    hi = NN;
    while (lo < hi) { int m = (lo + hi) >> 1; if (batch[m] < gidx + 1) lo = m + 1; else hi = m; }
    const int end = lo;
    float acc = 0.f;
    for (int n = beg + r; n < end; n += 4) acc += h[(size_t)n * 64 + o];
    part[r * 64 + o] = acc;
    __syncthreads();
    if (tid < 64) {
        const int cnt = end - beg;
        const float inv = (cnt > 0) ? 1.f / (float)cnt : 1.f;
        hrow[tid] = (part[tid] + part[64 + tid] + part[128 + tid] + part[192 + tid]) * inv;
    }
    __syncthreads();
    if (tid < 64) {
        float s = b1[tid];
#pragma unroll
        for (int k = 0; k < 64; ++k) s += hrow[k] * w1[k * 64 + tid];
        s = silu_f(s);
        float v = s * w2[tid];
#pragma unroll
        for (int d = 32; d > 0; d >>= 1) v += __shfl_down(v, d);
        if (tid == 0) out[gidx] = v + b2[0];
    }
}

extern "C" void kernel_launch(void* const* d_in, const int* in_sizes, int n_in,
                              void* d_out, int out_size, void* d_ws, size_t ws_size,
                              hipStream_t stream) {
    const float* x     = (const float*)d_in[0];
    const float* ea    = (const float*)d_in[1];
    const int*   ei    = (const int*)  d_in[2];
    const int*   batch = (const int*)  d_in[3];
    const float* pw    = (const float*)d_in[4];
    const float* pb    = (const float*)d_in[5];
    const float* ew1   = (const float*)d_in[6];
    const float* eb1   = (const float*)d_in[7];
    const float* ew2   = (const float*)d_in[8];
    const float* eb2   = (const float*)d_in[9];
    const float* rw    = (const float*)d_in[10];
    const float* cb    = (const float*)d_in[11];
    const float* hw1   = (const float*)d_in[12];
    const float* hb1   = (const float*)d_in[13];
    const float* hw2   = (const float*)d_in[14];
    const float* hb2   = (const float*)d_in[15];
    float* out = (float*)d_out;

    float* ws = (float*)d_ws;
    size_t off = 0;
    auto alloc = [&](size_t n) {
        float* p = ws + off;
        off += (n + 63) & ~(size_t)63;
        return p;
    };
    float* hA   = alloc((size_t)NN * 64);
    float* hBuf = alloc((size_t)NN * 64);
    float* msg  = alloc((size_t)NE * 64);
    float* Cbuf = alloc((size_t)NN * 64);
    float* invd = alloc(NN);
    int* off_s = (int*)alloc(NN + 1);
    int* off_d = (int*)alloc(NN + 1);
    int* cnt_s = (int*)alloc(NN);
    int* cnt_d = (int*)alloc(NN);
    int* cur_s = (int*)alloc(NN);
    int* cur_d = (int*)alloc(NN);
    int* eid_s = (int*)alloc(NE);
    int* eid_d = (int*)alloc(NE);
    short* packW = (short*)alloc(3 * PWL / 2 + 64);                 // 9.6 MB
    short* packH = (short*)alloc((size_t)NRT * 2 * 3 * WFRAG / 2 + 64); // 3.8 MB

    // g for all 3 layers (batched) if ws allows
    const size_t needG3 = (size_t)3 * NE * 64;
    const size_t padB10k = (size_t)((10000 + 31) / 32) * 32 * 4096;
    bool batchG = (off + needG3 + padB10k + 128) * sizeof(float) <= ws_size;
    float* gbuf = alloc(batchG ? needG3 : (size_t)NE * 64);

    int nch = 4992;   // multiple of 32 for clean row-tiles
    {
        auto fits = [&](int rows) {
            size_t padRows = (size_t)((rows + 31) / 32) * 32;
            return (off + padRows * 4096 + 64) * sizeof(float) <= ws_size;
        };
        if (fits(10000)) nch = 10000;
    }
    float* Bch = alloc((size_t)((nch + 31) / 32) * 32 * 4096);

    hipMemsetAsync(cnt_s, 0, NN * sizeof(int), stream);
    hipMemsetAsync(cnt_d, 0, NN * sizeof(int), stream);

    k_hist<<<dim3((NE + 255) / 256), dim3(256), 0, stream>>>(ei, cnt_s, cnt_d);
    k_scan2<<<dim3(1), dim3(1024), 0, stream>>>(cnt_s, cnt_d, off_s, off_d,
                                                cur_s, cur_d, invd);
    k_fill<<<dim3((NE + 255) / 256), dim3(256), 0, stream>>>(ei, off_s, cur_s, eid_s);
    k_fill<<<dim3((NE + 255) / 256), dim3(256), 0, stream>>>(ei + NE, off_d, cur_d, eid_d);

    // pack all layers' w2(+b2) into MFMA fragments (once)
    k_packw<<<dim3(NCT, 3), dim3(128), 0, stream>>>(ew2, eb2, packW);

    // h = x @ proj_w + proj_b
    k_rowmm<64, false, true><<<dim3(NN / 4), dim3(256), 0, stream>>>(x, pw, pb, hA, NN);

    if (batchG) {
        k_gmm3<<<dim3(NE / 4, 3), dim3(256), 0, stream>>>(ea, ew1, eb1, gbuf);
    }

    float* hcur = hA;
    float* hnxt = hBuf;
    for (int l = 0; l < NLAYERS; l++) {
        float* gl = batchG ? gbuf + (size_t)l * NE * 64 : gbuf;
        if (!batchG) {
            k_rowmm<16, true, true><<<dim3(NE / 4), dim3(256), 0, stream>>>(
                ea, ew1 + (size_t)l * EDIM * 64, eb1 + (size_t)l * 64, gl, NE);
        }
        k_packh<<<dim3(NRT), dim3(128), 0, stream>>>(hcur, packH);
        for (int n0 = 0; n0 < NN; n0 += nch) {
            const int n1 = (n0 + nch < NN) ? n0 + nch : NN;
            const int nCnt = n1 - n0;
            k_bgemm_mfma<<<dim3((nCnt + 31) / 32, 17), dim3(256), 0, stream>>>(
                packH, packW + (size_t)l * PWL, Bch, Cbuf, n0, n1);
            k_edge2<<<dim3((nCnt + 3) / 4), dim3(256), 0, stream>>>(
                gl, Bch, Cbuf, off_s, eid_s, msg, n0, nCnt);
        }
        k_aggfin<<<dim3(NN / 8), dim3(256), 0, stream>>>(
            hcur, msg, off_d, eid_d, invd, rw + (size_t)l * 64 * 64,
            cb + (size_t)l * 64, hnxt);
        float* t = hcur; hcur = hnxt; hnxt = t;
    }

    k_poolhead<<<dim3(NGRAPH), dim3(256), 0, stream>>>(
        hcur, batch, hw1, hb1, hw2, hb2, out);
}

// Round 14
// 388.542 us; speedup vs baseline: 1.6955x; 1.0249x over previous
//
#include <hip/hip_runtime.h>
#include <math.h>

#define NN 10000
#define NE 40000
#define NGRAPH 64
#define HID 64
#define EDIM 16
#define NLAYERS 3

#define NRT 625            // row tiles (16 nodes each)
#define NCT 260            // col tiles: 4096 (B) + 64 (C from b2)
#define WFRAG 512          // shorts per fragment-slot (64 lanes x 8)
#define PWL ((size_t)NCT * 2 * 3 * WFRAG)   // packed W shorts per layer

#define GN 16              // nodes per fused group
#define KPAD 68            // k-stride in Bt (floats)
#define JSTR (16 * KPAD + 4)   // 1092: j-stride (bank-rotating)

typedef __attribute__((ext_vector_type(8))) short bf8v;
typedef __attribute__((ext_vector_type(4))) float f32x4;

__device__ __forceinline__ float silu_f(float x) { return x / (1.f + expf(-x)); }

__device__ __forceinline__ unsigned short f2bf(float f) {
    unsigned int u = __float_as_uint(f);
    u += 0x7fff + ((u >> 16) & 1);
    return (unsigned short)(u >> 16);
}
__device__ __forceinline__ float bf2f(unsigned short s) {
    return __uint_as_float(((unsigned int)s) << 16);
}
__device__ __forceinline__ void split3f(float v, short& a, short& b, short& c) {
    unsigned short u1 = f2bf(v);      float f1 = bf2f(u1);
    unsigned short u2 = f2bf(v - f1); float f2 = bf2f(u2);
    unsigned short u3 = f2bf(v - f1 - f2);
    a = (short)u1; b = (short)u2; c = (short)u3;
}

// ---------------- small row GEMM ----------------
template<int K, bool DO_SILU, bool HAS_BIAS>
__global__ __launch_bounds__(256)
void k_rowmm(const float* __restrict__ A, const float* __restrict__ W,
             const float* __restrict__ bias, float* __restrict__ out, int M) {
    __shared__ float Ws[K * 64];
    __shared__ float As[4 * K];
    const int tid = threadIdx.x;
    for (int idx = tid; idx < K * 64; idx += 256) Ws[idx] = W[idx];
    const int r0 = blockIdx.x * 4;
    for (int idx = tid; idx < 4 * K; idx += 256) {
        int r = r0 + idx / K;
        As[idx] = (r < M) ? A[(size_t)r * K + (idx % K)] : 0.f;
    }
    __syncthreads();
    const int rr = tid >> 6, c = tid & 63;
    const int r = r0 + rr;
    if (r >= M) return;
    float s = HAS_BIAS ? bias[c] : 0.f;
#pragma unroll
    for (int k = 0; k < K; k++) s += As[rr * K + k] * Ws[k * 64 + c];
    if (DO_SILU) s = silu_f(s);
    out[(size_t)r * 64 + c] = s;
}

// ---------------- batched edge-MLP for ALL layers ----------------
__global__ __launch_bounds__(256)
void k_gmm3(const float* __restrict__ ea, const float* __restrict__ ew1,
            const float* __restrict__ eb1, float* __restrict__ g3) {
    const int l = blockIdx.y;
    const float* W = ew1 + (size_t)l * EDIM * 64;
    const float* bias = eb1 + (size_t)l * 64;
    float* out = g3 + (size_t)l * NE * 64;
    __shared__ float Ws[EDIM * 64];
    __shared__ float As[4 * EDIM];
    const int tid = threadIdx.x;
    for (int idx = tid; idx < EDIM * 64; idx += 256) Ws[idx] = W[idx];
    const int r0 = blockIdx.x * 4;
    if (tid < 4 * EDIM) As[tid] = ea[(size_t)r0 * EDIM + tid];
    __syncthreads();
    const int rr = tid >> 6, c = tid & 63;
    float s = bias[c];
#pragma unroll
    for (int k = 0; k < EDIM; k++) s += As[rr * EDIM + k] * Ws[k * 64 + c];
    out[(size_t)(r0 + rr) * 64 + c] = silu_f(s);
}

// ---------------- degree histograms ----------------
__global__ void k_hist(const int* __restrict__ ei, int* __restrict__ cnt_s,
                       int* __restrict__ cnt_d) {
    int e = blockIdx.x * 256 + threadIdx.x;
    if (e >= NE) return;
    atomicAdd(&cnt_s[ei[e]], 1);
    atomicAdd(&cnt_d[ei[NE + e]], 1);
}

// ---------------- single-block: both scans + invdeg ----------------
__global__ __launch_bounds__(1024)
void k_scan2(const int* __restrict__ cnt_s, const int* __restrict__ cnt_d,
             int* __restrict__ off_s, int* __restrict__ off_d,
             int* __restrict__ cur_s, int* __restrict__ cur_d,
             float* __restrict__ invd) {
    __shared__ int part[1024];
    const int t = threadIdx.x;
    const int CH = (NN + 1023) / 1024;
    const int base0 = t * CH;
#pragma unroll
    for (int pass = 0; pass < 2; ++pass) {
        const int* cnt = pass ? cnt_d : cnt_s;
        int* off = pass ? off_d : off_s;
        int* cur = pass ? cur_d : cur_s;
        int s = 0;
        for (int i = 0; i < CH; i++) {
            int idx = base0 + i;
            if (idx < NN) s += cnt[idx];
        }
        part[t] = s;
        __syncthreads();
        for (int d = 1; d < 1024; d <<= 1) {
            int v = (t >= d) ? part[t - d] : 0;
            __syncthreads();
            part[t] += v;
            __syncthreads();
        }
        int run = (t == 0) ? 0 : part[t - 1];
        for (int i = 0; i < CH; i++) {
            int idx = base0 + i;
            if (idx < NN) {
                off[idx] = run;
                int c = cnt[idx];
                if (pass) invd[idx] = (c > 0) ? 1.f / (float)c : 0.f;
                run += c;
                cur[idx] = 0;
            }
        }
        if (t == 1023) off[NN] = run;
        __syncthreads();
    }
}

__global__ void k_fill(const int* __restrict__ keys, const int* __restrict__ off,
                       int* __restrict__ cur, int* __restrict__ eid) {
    int e = blockIdx.x * 256 + threadIdx.x;
    if (e >= NE) return;
    int s = keys[e];
    int p = atomicAdd(&cur[s], 1);
    eid[off[s] + p] = e;
}

// ---------------- pack w2 (+b2 as cols 4096..4159) into MFMA B-fragments ----------
__global__ __launch_bounds__(128)
void k_packw(const float* __restrict__ ew2, const float* __restrict__ eb2,
             short* __restrict__ pw) {
    const int ct = blockIdx.x;
    const int lay = blockIdx.y;
    const int t = threadIdx.x;
    const int l = t & 63, ks = t >> 6;
    const int col = ct * 16 + (l & 15);
    const int i0 = ks * 32 + ((l >> 4) << 3);
    bf8v v1, v2, v3;
#pragma unroll
    for (int tt = 0; tt < 8; ++tt) {
        const int i = i0 + tt;
        float v;
        if (col < 4096)
            v = ew2[(size_t)lay * 262144 + (size_t)(col >> 6) * 4096 + i * 64 + (col & 63)];
        else
            v = eb2[(size_t)lay * 4096 + i * 64 + (col - 4096)];
        short a, b, c;
        split3f(v, a, b, c);
        v1[tt] = a; v2[tt] = b; v3[tt] = c;
    }
    short* dst = pw + ((((size_t)lay * NCT + ct) * 2 + ks) * 3) * WFRAG + l * 8;
    *reinterpret_cast<bf8v*>(dst)        = v1;
    *reinterpret_cast<bf8v*>(dst + 512)  = v2;
    *reinterpret_cast<bf8v*>(dst + 1024) = v3;
}

// ---------------- pack h into MFMA A-fragments (per layer) ----------------
__global__ __launch_bounds__(128)
void k_packh(const float* __restrict__ h, short* __restrict__ ph) {
    const int rt = blockIdx.x;
    const int t = threadIdx.x;
    const int l = t & 63, ks = t >> 6;
    const int row = rt * 16 + (l & 15);
    const int i0 = ks * 32 + ((l >> 4) << 3);
    const float* hp = h + (size_t)row * 64 + i0;
    bf8v v1, v2, v3;
#pragma unroll
    for (int tt = 0; tt < 8; ++tt) {
        short a, b, c;
        split3f(hp[tt], a, b, c);
        v1[tt] = a; v2[tt] = b; v3[tt] = c;
    }
    short* dst = ph + (((size_t)rt * 2 + ks) * 3) * WFRAG + l * 8;
    *reinterpret_cast<bf8v*>(dst)        = v1;
    *reinterpret_cast<bf8v*>(dst + 512)  = v2;
    *reinterpret_cast<bf8v*>(dst + 1024) = v3;
}

// ---------------- FUSED: MFMA B-subtile in LDS + edge message store ----------------
// grid (625, 4): block = (16-node group) x (o-quarter). Quarter q covers o in
// [q*16, q*16+16): col-tiles ct = k*4+q (k=0..63) + C-tile ct = 256+q.
// Bt[j][o'][k] in LDS (69.9KB padded) -> 2 blocks/CU. No B to HBM.
__global__ __launch_bounds__(256, 2)
void k_msgfused(const short* __restrict__ ph, const short* __restrict__ pw,
                const float* __restrict__ g, const int* __restrict__ csr_off,
                const int* __restrict__ csr_eid, float* __restrict__ msg) {
    __shared__ float Bt[16 * JSTR];
    __shared__ float C_s[16 * 16];
    __shared__ int offs[GN + 1];

    const int grp = blockIdx.x, q = blockIdx.y;
    const int lane = threadIdx.x & 63;
    const int wid  = threadIdx.x >> 6;

    if (threadIdx.x <= GN) offs[threadIdx.x] = csr_off[grp * GN + threadIdx.x];

    // A fragments for this row-tile (verified layout, round 13)
    bf8v A[2][3];
#pragma unroll
    for (int ks = 0; ks < 2; ++ks)
#pragma unroll
        for (int sp = 0; sp < 3; ++sp)
            A[ks][sp] = *reinterpret_cast<const bf8v*>(
                ph + (((size_t)grp * 2 + ks) * 3 + sp) * WFRAG + lane * 8);

    const int oq_w = lane & 15;            // o' within quarter (C/D col)
    const int jb   = (lane >> 4) << 2;     // C/D row base

    // ---- MFMA phase: wave wid covers k = wid*16 .. +16 ----
#pragma unroll 4
    for (int kk = 0; kk < 16; ++kk) {
        const int k = wid * 16 + kk;
        const int ct = k * 4 + q;
        bf8v Bf[2][3];
#pragma unroll
        for (int ks = 0; ks < 2; ++ks)
#pragma unroll
            for (int sp = 0; sp < 3; ++sp)
                Bf[ks][sp] = *reinterpret_cast<const bf8v*>(
                    pw + (((size_t)ct * 2 + ks) * 3 + sp) * WFRAG + lane * 8);
        f32x4 acc = {0.f, 0.f, 0.f, 0.f};
#pragma unroll
        for (int ks = 0; ks < 2; ++ks) {
            acc = __builtin_amdgcn_mfma_f32_16x16x32_bf16(A[ks][0], Bf[ks][0], acc, 0, 0, 0);
            acc = __builtin_amdgcn_mfma_f32_16x16x32_bf16(A[ks][0], Bf[ks][1], acc, 0, 0, 0);
            acc = __builtin_amdgcn_mfma_f32_16x16x32_bf16(A[ks][1], Bf[ks][0], acc, 0, 0, 0);
            acc = __builtin_amdgcn_mfma_f32_16x16x32_bf16(A[ks][0], Bf[ks][2], acc, 0, 0, 0);
            acc = __builtin_amdgcn_mfma_f32_16x16x32_bf16(A[ks][1], Bf[ks][1], acc, 0, 0, 0);
            acc = __builtin_amdgcn_mfma_f32_16x16x32_bf16(A[ks][2], Bf[ks][0], acc, 0, 0, 0);
        }
#pragma unroll
        for (int r = 0; r < 4; ++r)
            Bt[(jb + r) * JSTR + oq_w * KPAD + k] = acc[r];
    }
    if (wid == 3) {   // ---- C tile (b2 cols) ----
        const int ct = 256 + q;
        bf8v Bf[2][3];
#pragma unroll
        for (int ks = 0; ks < 2; ++ks)
#pragma unroll
            for (int sp = 0; sp < 3; ++sp)
                Bf[ks][sp] = *reinterpret_cast<const bf8v*>(
                    pw + (((size_t)ct * 2 + ks) * 3 + sp) * WFRAG + lane * 8);
        f32x4 acc = {0.f, 0.f, 0.f, 0.f};
#pragma unroll
        for (int ks = 0; ks < 2; ++ks) {
            acc = __builtin_amdgcn_mfma_f32_16x16x32_bf16(A[ks][0], Bf[ks][0], acc, 0, 0, 0);
            acc = __builtin_amdgcn_mfma_f32_16x16x32_bf16(A[ks][0], Bf[ks][1], acc, 0, 0, 0);
            acc = __builtin_amdgcn_mfma_f32_16x16x32_bf16(A[ks][1], Bf[ks][0], acc, 0, 0, 0);
            acc = __builtin_amdgcn_mfma_f32_16x16x32_bf16(A[ks][0], Bf[ks][2], acc, 0, 0, 0);
            acc = __builtin_amdgcn_mfma_f32_16x16x32_bf16(A[ks][1], Bf[ks][1], acc, 0, 0, 0);
            acc = __builtin_amdgcn_mfma_f32_16x16x32_bf16(A[ks][2], Bf[ks][0], acc, 0, 0, 0);
        }
#pragma unroll
        for (int r = 0; r < 4; ++r)
            C_s[(jb + r) * 16 + oq_w] = acc[r];
    }
    __syncthreads();

    // ---- edge phase: 16 lanes per edge; msg[e, q*16+o'] ----
    const int P0 = offs[0];
    const int Etot = offs[GN] - P0;
    const int oq = threadIdx.x & 15;
    const int eq = threadIdx.x >> 4;       // 16 edge slots in flight
    for (int slot = eq; slot < Etot; slot += 16) {
        const int gpos = P0 + slot;
        int j = 0;
#pragma unroll
        for (int t = 1; t < GN; ++t) j += (gpos >= offs[t]) ? 1 : 0;
        const int e = csr_eid[gpos];
        const float* grow = g + (size_t)e * 64;
        const float* Bj = Bt + j * JSTR + oq * KPAD;
        float m = C_s[j * 16 + oq];
#pragma unroll
        for (int k4 = 0; k4 < 16; ++k4) {
            const float4 gv = *(const float4*)(grow + k4 * 4);   // quad-broadcast
            const float4 bv = *(const float4*)(Bj + k4 * 4);
            m += gv.x * bv.x + gv.y * bv.y + gv.z * bv.z + gv.w * bv.w;
        }
        msg[(size_t)e * 64 + q * 16 + oq] = m;
    }
}

// ---------------- gather by dst + root GEMM + silu (8 rows/block) ----------------
__global__ __launch_bounds__(256)
void k_aggfin(const float* __restrict__ h, const float* __restrict__ msg,
              const int* __restrict__ off2, const int* __restrict__ eid2,
              const float* __restrict__ invd, const float* __restrict__ rw,
              const float* __restrict__ cb, float* __restrict__ hout) {
    __shared__ float Ws[64 * 64];
    __shared__ float As[8 * 64];
    __shared__ int eoff[9];
    const int tid = threadIdx.x;
    for (int idx = tid; idx < 64 * 64; idx += 256) Ws[idx] = rw[idx];
    const int r0 = blockIdx.x * 8;
    for (int idx = tid; idx < 8 * 64; idx += 256) As[idx] = h[(size_t)r0 * 64 + idx];
    if (tid < 9) eoff[tid] = off2[r0 + tid];
    __syncthreads();
    const int rr = tid >> 6, c = tid & 63;
#pragma unroll
    for (int half = 0; half < 2; ++half) {
        const int lr = half * 4 + rr;
        const int r = r0 + lr;
        float a = 0.f;
        for (int p = eoff[lr]; p < eoff[lr + 1]; ++p) {
            a += msg[(size_t)eid2[p] * 64 + c];
        }
        float s = cb[c] + a * invd[r];
        const float* Ar = As + lr * 64;
#pragma unroll
        for (int k = 0; k < 64; k++) s += Ar[k] * Ws[k * 64 + c];
        hout[(size_t)r * 64 + c] = silu_f(s);
    }
}

// ---------------- fused mean-pool + head MLP ----------------
__global__ __launch_bounds__(256)
void k_poolhead(const float* __restrict__ h, const int* __restrict__ batch,
                const float* __restrict__ w1, const float* __restrict__ b1,
                const float* __restrict__ w2, const float* __restrict__ b2,
                float* __restrict__ out) {
    __shared__ float part[4 * 64];
    __shared__ float hrow[64];
    const int gidx = blockIdx.x;
    const int tid = threadIdx.x;
    const int r = tid >> 6, o = tid & 63;
    int lo = 0, hi = NN;
    while (lo < hi) { int m = (lo + hi) >> 1; if (batch[m] < gidx) lo = m + 1; else hi = m; }
    const int beg = lo;
    hi = NN;
    while (lo < hi) { int m = (lo + hi) >> 1; if (batch[m] < gidx + 1) lo = m + 1; else hi = m; }
    const int end = lo;
    float acc = 0.f;
    for (int n = beg + r; n < end; n += 4) acc += h[(size_t)n * 64 + o];
    part[r * 64 + o] = acc;
    __syncthreads();
    if (tid < 64) {
        const int cnt = end - beg;
        const float inv = (cnt > 0) ? 1.f / (float)cnt : 1.f;
        hrow[tid] = (part[tid] + part[64 + tid] + part[128 + tid] + part[192 + tid]) * inv;
    }
    __syncthreads();
    if (tid < 64) {
        float s = b1[tid];
#pragma unroll
        for (int k = 0; k < 64; ++k) s += hrow[k] * w1[k * 64 + tid];
        s = silu_f(s);
        float v = s * w2[tid];
#pragma unroll
        for (int d = 32; d > 0; d >>= 1) v += __shfl_down(v, d);
        if (tid == 0) out[gidx] = v + b2[0];
    }
}

extern "C" void kernel_launch(void* const* d_in, const int* in_sizes, int n_in,
                              void* d_out, int out_size, void* d_ws, size_t ws_size,
                              hipStream_t stream) {
    const float* x     = (const float*)d_in[0];
    const float* ea    = (const float*)d_in[1];
    const int*   ei    = (const int*)  d_in[2];
    const int*   batch = (const int*)  d_in[3];
    const float* pw    = (const float*)d_in[4];
    const float* pb    = (const float*)d_in[5];
    const float* ew1   = (const float*)d_in[6];
    const float* eb1   = (const float*)d_in[7];
    const float* ew2   = (const float*)d_in[8];
    const float* eb2   = (const float*)d_in[9];
    const float* rw    = (const float*)d_in[10];
    const float* cb    = (const float*)d_in[11];
    const float* hw1   = (const float*)d_in[12];
    const float* hb1   = (const float*)d_in[13];
    const float* hw2   = (const float*)d_in[14];
    const float* hb2   = (const float*)d_in[15];
    float* out = (float*)d_out;

    float* ws = (float*)d_ws;
    size_t off = 0;
    auto alloc = [&](size_t n) {
        float* p = ws + off;
        off += (n + 63) & ~(size_t)63;
        return p;
    };
    float* hA   = alloc((size_t)NN * 64);
    float* hBuf = alloc((size_t)NN * 64);
    float* msg  = alloc((size_t)NE * 64);
    float* invd = alloc(NN);
    int* off_s = (int*)alloc(NN + 1);
    int* off_d = (int*)alloc(NN + 1);
    int* cnt_s = (int*)alloc(NN);
    int* cnt_d = (int*)alloc(NN);
    int* cur_s = (int*)alloc(NN);
    int* cur_d = (int*)alloc(NN);
    int* eid_s = (int*)alloc(NE);
    int* eid_d = (int*)alloc(NE);
    short* packW = (short*)alloc(3 * PWL / 2 + 64);
    short* packH = (short*)alloc((size_t)NRT * 2 * 3 * WFRAG / 2 + 64);

    const size_t needG3 = (size_t)3 * NE * 64;
    bool batchG = (off + needG3 + 128) * sizeof(float) <= ws_size;
    float* gbuf = alloc(batchG ? needG3 : (size_t)NE * 64);

    hipMemsetAsync(cnt_s, 0, NN * sizeof(int), stream);
    hipMemsetAsync(cnt_d, 0, NN * sizeof(int), stream);

    k_hist<<<dim3((NE + 255) / 256), dim3(256), 0, stream>>>(ei, cnt_s, cnt_d);
    k_scan2<<<dim3(1), dim3(1024), 0, stream>>>(cnt_s, cnt_d, off_s, off_d,
                                                cur_s, cur_d, invd);
    k_fill<<<dim3((NE + 255) / 256), dim3(256), 0, stream>>>(ei, off_s, cur_s, eid_s);
    k_fill<<<dim3((NE + 255) / 256), dim3(256), 0, stream>>>(ei + NE, off_d, cur_d, eid_d);

    k_packw<<<dim3(NCT, 3), dim3(128), 0, stream>>>(ew2, eb2, packW);

    k_rowmm<64, false, true><<<dim3(NN / 4), dim3(256), 0, stream>>>(x, pw, pb, hA, NN);

    if (batchG) {
        k_gmm3<<<dim3(NE / 4, 3), dim3(256), 0, stream>>>(ea, ew1, eb1, gbuf);
    }

    float* hcur = hA;
    float* hnxt = hBuf;
    for (int l = 0; l < NLAYERS; l++) {
        float* gl = batchG ? gbuf + (size_t)l * NE * 64 : gbuf;
        if (!batchG) {
            k_rowmm<16, true, true><<<dim3(NE / 4), dim3(256), 0, stream>>>(
                ea, ew1 + (size_t)l * EDIM * 64, eb1 + (size_t)l * 64, gl, NE);
        }
        k_packh<<<dim3(NRT), dim3(128), 0, stream>>>(hcur, packH);
        k_msgfused<<<dim3(NRT, 4), dim3(256), 0, stream>>>(
            packH, packW + (size_t)l * PWL, gl, off_s, eid_s, msg);
        k_aggfin<<<dim3(NN / 8), dim3(256), 0, stream>>>(
            hcur, msg, off_d, eid_d, invd, rw + (size_t)l * 64 * 64,
            cb + (size_t)l * 64, hnxt);
        float* t = hcur; hcur = hnxt; hnxt = t;
    }

    k_poolhead<<<dim3(NGRAPH), dim3(256), 0, stream>>>(
        hcur, batch, hw1, hb1, hw2, hb2, out);
}

// Round 15
// 349.094 us; speedup vs baseline: 1.8871x; 1.1130x over previous
//
#include <hip/hip_runtime.h>
#include <math.h>

#define NN 10000
#define NE 40000
#define NGRAPH 64
#define HID 64
#define EDIM 16
#define NLAYERS 3

#define NRT 625            // row tiles (16 nodes each)
#define NCT 260            // col tiles: 4096 (B) + 64 (C from b2)
#define WFRAG 512          // shorts per fragment-slot (64 lanes x 8)
#define PWL ((size_t)NCT * 2 * 3 * WFRAG)   // packed W shorts per layer

#define GN 16              // nodes per fused group
#define KPAD 68            // k-stride in Bt (floats)
#define JSTR (16 * KPAD + 4)   // 1092: j-stride (bank-rotating)

typedef __attribute__((ext_vector_type(8))) short bf8v;
typedef __attribute__((ext_vector_type(4))) float f32x4;

__device__ __forceinline__ float silu_f(float x) { return x / (1.f + expf(-x)); }

__device__ __forceinline__ unsigned short f2bf(float f) {
    unsigned int u = __float_as_uint(f);
    u += 0x7fff + ((u >> 16) & 1);
    return (unsigned short)(u >> 16);
}
__device__ __forceinline__ float bf2f(unsigned short s) {
    return __uint_as_float(((unsigned int)s) << 16);
}
__device__ __forceinline__ void split3f(float v, short& a, short& b, short& c) {
    unsigned short u1 = f2bf(v);      float f1 = bf2f(u1);
    unsigned short u2 = f2bf(v - f1); float f2 = bf2f(u2);
    unsigned short u3 = f2bf(v - f1 - f2);
    a = (short)u1; b = (short)u2; c = (short)u3;
}

// ---------------- small row GEMM ----------------
template<int K, bool DO_SILU, bool HAS_BIAS>
__global__ __launch_bounds__(256)
void k_rowmm(const float* __restrict__ A, const float* __restrict__ W,
             const float* __restrict__ bias, float* __restrict__ out, int M) {
    __shared__ float Ws[K * 64];
    __shared__ float As[4 * K];
    const int tid = threadIdx.x;
    for (int idx = tid; idx < K * 64; idx += 256) Ws[idx] = W[idx];
    const int r0 = blockIdx.x * 4;
    for (int idx = tid; idx < 4 * K; idx += 256) {
        int r = r0 + idx / K;
        As[idx] = (r < M) ? A[(size_t)r * K + (idx % K)] : 0.f;
    }
    __syncthreads();
    const int rr = tid >> 6, c = tid & 63;
    const int r = r0 + rr;
    if (r >= M) return;
    float s = HAS_BIAS ? bias[c] : 0.f;
#pragma unroll
    for (int k = 0; k < K; k++) s += As[rr * K + k] * Ws[k * 64 + c];
    if (DO_SILU) s = silu_f(s);
    out[(size_t)r * 64 + c] = s;
}

// ---------------- batched edge-MLP for ALL layers ----------------
__global__ __launch_bounds__(256)
void k_gmm3(const float* __restrict__ ea, const float* __restrict__ ew1,
            const float* __restrict__ eb1, float* __restrict__ g3) {
    const int l = blockIdx.y;
    const float* W = ew1 + (size_t)l * EDIM * 64;
    const float* bias = eb1 + (size_t)l * 64;
    float* out = g3 + (size_t)l * NE * 64;
    __shared__ float Ws[EDIM * 64];
    __shared__ float As[4 * EDIM];
    const int tid = threadIdx.x;
    for (int idx = tid; idx < EDIM * 64; idx += 256) Ws[idx] = W[idx];
    const int r0 = blockIdx.x * 4;
    if (tid < 4 * EDIM) As[tid] = ea[(size_t)r0 * EDIM + tid];
    __syncthreads();
    const int rr = tid >> 6, c = tid & 63;
    float s = bias[c];
#pragma unroll
    for (int k = 0; k < EDIM; k++) s += As[rr * EDIM + k] * Ws[k * 64 + c];
    out[(size_t)(r0 + rr) * 64 + c] = silu_f(s);
}

// ---------------- degree histograms ----------------
__global__ void k_hist(const int* __restrict__ ei, int* __restrict__ cnt_s,
                       int* __restrict__ cnt_d) {
    int e = blockIdx.x * 256 + threadIdx.x;
    if (e >= NE) return;
    atomicAdd(&cnt_s[ei[e]], 1);
    atomicAdd(&cnt_d[ei[NE + e]], 1);
}

// ---------------- single-block: both scans + invdeg ----------------
__global__ __launch_bounds__(1024)
void k_scan2(const int* __restrict__ cnt_s, const int* __restrict__ cnt_d,
             int* __restrict__ off_s, int* __restrict__ off_d,
             int* __restrict__ cur_s, int* __restrict__ cur_d,
             float* __restrict__ invd) {
    __shared__ int part[1024];
    const int t = threadIdx.x;
    const int CH = (NN + 1023) / 1024;
    const int base0 = t * CH;
#pragma unroll
    for (int pass = 0; pass < 2; ++pass) {
        const int* cnt = pass ? cnt_d : cnt_s;
        int* off = pass ? off_d : off_s;
        int* cur = pass ? cur_d : cur_s;
        int s = 0;
        for (int i = 0; i < CH; i++) {
            int idx = base0 + i;
            if (idx < NN) s += cnt[idx];
        }
        part[t] = s;
        __syncthreads();
        for (int d = 1; d < 1024; d <<= 1) {
            int v = (t >= d) ? part[t - d] : 0;
            __syncthreads();
            part[t] += v;
            __syncthreads();
        }
        int run = (t == 0) ? 0 : part[t - 1];
        for (int i = 0; i < CH; i++) {
            int idx = base0 + i;
            if (idx < NN) {
                off[idx] = run;
                int c = cnt[idx];
                if (pass) invd[idx] = (c > 0) ? 1.f / (float)c : 0.f;
                run += c;
                cur[idx] = 0;
            }
        }
        if (t == 1023) off[NN] = run;
        __syncthreads();
    }
}

__global__ void k_fill(const int* __restrict__ keys, const int* __restrict__ off,
                       int* __restrict__ cur, int* __restrict__ eid) {
    int e = blockIdx.x * 256 + threadIdx.x;
    if (e >= NE) return;
    int s = keys[e];
    int p = atomicAdd(&cur[s], 1);
    eid[off[s] + p] = e;
}

// ---------------- pack w2 (+b2 as cols 4096..4159) into MFMA B-fragments ----------
__global__ __launch_bounds__(128)
void k_packw(const float* __restrict__ ew2, const float* __restrict__ eb2,
             short* __restrict__ pw) {
    const int ct = blockIdx.x;
    const int lay = blockIdx.y;
    const int t = threadIdx.x;
    const int l = t & 63, ks = t >> 6;
    const int col = ct * 16 + (l & 15);
    const int i0 = ks * 32 + ((l >> 4) << 3);
    bf8v v1, v2, v3;
#pragma unroll
    for (int tt = 0; tt < 8; ++tt) {
        const int i = i0 + tt;
        float v;
        if (col < 4096)
            v = ew2[(size_t)lay * 262144 + (size_t)(col >> 6) * 4096 + i * 64 + (col & 63)];
        else
            v = eb2[(size_t)lay * 4096 + i * 64 + (col - 4096)];
        short a, b, c;
        split3f(v, a, b, c);
        v1[tt] = a; v2[tt] = b; v3[tt] = c;
    }
    short* dst = pw + ((((size_t)lay * NCT + ct) * 2 + ks) * 3) * WFRAG + l * 8;
    *reinterpret_cast<bf8v*>(dst)        = v1;
    *reinterpret_cast<bf8v*>(dst + 512)  = v2;
    *reinterpret_cast<bf8v*>(dst + 1024) = v3;
}

// ---------------- pack h into MFMA A-fragments (per layer) ----------------
__global__ __launch_bounds__(128)
void k_packh(const float* __restrict__ h, short* __restrict__ ph) {
    const int rt = blockIdx.x;
    const int t = threadIdx.x;
    const int l = t & 63, ks = t >> 6;
    const int row = rt * 16 + (l & 15);
    const int i0 = ks * 32 + ((l >> 4) << 3);
    const float* hp = h + (size_t)row * 64 + i0;
    bf8v v1, v2, v3;
#pragma unroll
    for (int tt = 0; tt < 8; ++tt) {
        short a, b, c;
        split3f(hp[tt], a, b, c);
        v1[tt] = a; v2[tt] = b; v3[tt] = c;
    }
    short* dst = ph + (((size_t)rt * 2 + ks) * 3) * WFRAG + l * 8;
    *reinterpret_cast<bf8v*>(dst)        = v1;
    *reinterpret_cast<bf8v*>(dst + 512)  = v2;
    *reinterpret_cast<bf8v*>(dst + 1024) = v3;
}

// ---------------- FUSED: MFMA B-subtile in LDS + edge message store (v2) ----------
// 512 threads = 8 waves (was 4): same 71KB LDS -> still 2 blocks/CU, but 16
// waves/CU (4/SIMD) doubles latency hiding on the L2 fragment loads.
// Wave w covers k = w*8..+8; wave 7 also does the C (b2) tile.
__global__ __launch_bounds__(512, 4)
void k_msgfused(const short* __restrict__ ph, const short* __restrict__ pw,
                const float* __restrict__ g, const int* __restrict__ csr_off,
                const int* __restrict__ csr_eid, float* __restrict__ msg) {
    __shared__ float Bt[16 * JSTR];
    __shared__ float C_s[16 * 16];
    __shared__ int offs[GN + 1];

    const int grp = blockIdx.x, q = blockIdx.y;
    const int lane = threadIdx.x & 63;
    const int wid  = threadIdx.x >> 6;     // 0..7

    if (threadIdx.x <= GN) offs[threadIdx.x] = csr_off[grp * GN + threadIdx.x];

    // A fragments for this row-tile (verified layout, round 13)
    bf8v A[2][3];
#pragma unroll
    for (int ks = 0; ks < 2; ++ks)
#pragma unroll
        for (int sp = 0; sp < 3; ++sp)
            A[ks][sp] = *reinterpret_cast<const bf8v*>(
                ph + (((size_t)grp * 2 + ks) * 3 + sp) * WFRAG + lane * 8);

    const int oq_w = lane & 15;            // o' within quarter (C/D col)
    const int jb   = (lane >> 4) << 2;     // C/D row base

    // ---- MFMA phase: wave wid covers k = wid*8 .. +8 ----
#pragma unroll 4
    for (int kk = 0; kk < 8; ++kk) {
        const int k = wid * 8 + kk;
        const int ct = k * 4 + q;
        bf8v Bf[2][3];
#pragma unroll
        for (int ks = 0; ks < 2; ++ks)
#pragma unroll
            for (int sp = 0; sp < 3; ++sp)
                Bf[ks][sp] = *reinterpret_cast<const bf8v*>(
                    pw + (((size_t)ct * 2 + ks) * 3 + sp) * WFRAG + lane * 8);
        f32x4 acc = {0.f, 0.f, 0.f, 0.f};
#pragma unroll
        for (int ks = 0; ks < 2; ++ks) {
            acc = __builtin_amdgcn_mfma_f32_16x16x32_bf16(A[ks][0], Bf[ks][0], acc, 0, 0, 0);
            acc = __builtin_amdgcn_mfma_f32_16x16x32_bf16(A[ks][0], Bf[ks][1], acc, 0, 0, 0);
            acc = __builtin_amdgcn_mfma_f32_16x16x32_bf16(A[ks][1], Bf[ks][0], acc, 0, 0, 0);
            acc = __builtin_amdgcn_mfma_f32_16x16x32_bf16(A[ks][0], Bf[ks][2], acc, 0, 0, 0);
            acc = __builtin_amdgcn_mfma_f32_16x16x32_bf16(A[ks][1], Bf[ks][1], acc, 0, 0, 0);
            acc = __builtin_amdgcn_mfma_f32_16x16x32_bf16(A[ks][2], Bf[ks][0], acc, 0, 0, 0);
        }
#pragma unroll
        for (int r = 0; r < 4; ++r)
            Bt[(jb + r) * JSTR + oq_w * KPAD + k] = acc[r];
    }
    if (wid == 7) {   // ---- C tile (b2 cols) ----
        const int ct = 256 + q;
        bf8v Bf[2][3];
#pragma unroll
        for (int ks = 0; ks < 2; ++ks)
#pragma unroll
            for (int sp = 0; sp < 3; ++sp)
                Bf[ks][sp] = *reinterpret_cast<const bf8v*>(
                    pw + (((size_t)ct * 2 + ks) * 3 + sp) * WFRAG + lane * 8);
        f32x4 acc = {0.f, 0.f, 0.f, 0.f};
#pragma unroll
        for (int ks = 0; ks < 2; ++ks) {
            acc = __builtin_amdgcn_mfma_f32_16x16x32_bf16(A[ks][0], Bf[ks][0], acc, 0, 0, 0);
            acc = __builtin_amdgcn_mfma_f32_16x16x32_bf16(A[ks][0], Bf[ks][1], acc, 0, 0, 0);
            acc = __builtin_amdgcn_mfma_f32_16x16x32_bf16(A[ks][1], Bf[ks][0], acc, 0, 0, 0);
            acc = __builtin_amdgcn_mfma_f32_16x16x32_bf16(A[ks][0], Bf[ks][2], acc, 0, 0, 0);
            acc = __builtin_amdgcn_mfma_f32_16x16x32_bf16(A[ks][1], Bf[ks][1], acc, 0, 0, 0);
            acc = __builtin_amdgcn_mfma_f32_16x16x32_bf16(A[ks][2], Bf[ks][0], acc, 0, 0, 0);
        }
#pragma unroll
        for (int r = 0; r < 4; ++r)
            C_s[(jb + r) * 16 + oq_w] = acc[r];
    }
    __syncthreads();

    // ---- edge phase: 16 lanes per edge; 32 slots in flight ----
    const int P0 = offs[0];
    const int Etot = offs[GN] - P0;
    const int oq = threadIdx.x & 15;
    const int eq = threadIdx.x >> 4;       // 0..31
    for (int slot = eq; slot < Etot; slot += 32) {
        const int gpos = P0 + slot;
        int j = 0;
#pragma unroll
        for (int t = 1; t < GN; ++t) j += (gpos >= offs[t]) ? 1 : 0;
        const int e = csr_eid[gpos];
        const float* grow = g + (size_t)e * 64;
        const float* Bj = Bt + j * JSTR + oq * KPAD;
        float m = C_s[j * 16 + oq];
#pragma unroll
        for (int k4 = 0; k4 < 16; ++k4) {
            const float4 gv = *(const float4*)(grow + k4 * 4);   // quad-broadcast
            const float4 bv = *(const float4*)(Bj + k4 * 4);
            m += gv.x * bv.x + gv.y * bv.y + gv.z * bv.z + gv.w * bv.w;
        }
        msg[(size_t)e * 64 + q * 16 + oq] = m;
    }
}

// ---------------- gather by dst + root GEMM + silu (8 rows/block) ----------------
__global__ __launch_bounds__(256)
void k_aggfin(const float* __restrict__ h, const float* __restrict__ msg,
              const int* __restrict__ off2, const int* __restrict__ eid2,
              const float* __restrict__ invd, const float* __restrict__ rw,
              const float* __restrict__ cb, float* __restrict__ hout) {
    __shared__ float Ws[64 * 64];
    __shared__ float As[8 * 64];
    __shared__ int eoff[9];
    const int tid = threadIdx.x;
    for (int idx = tid; idx < 64 * 64; idx += 256) Ws[idx] = rw[idx];
    const int r0 = blockIdx.x * 8;
    for (int idx = tid; idx < 8 * 64; idx += 256) As[idx] = h[(size_t)r0 * 64 + idx];
    if (tid < 9) eoff[tid] = off2[r0 + tid];
    __syncthreads();
    const int rr = tid >> 6, c = tid & 63;
#pragma unroll
    for (int half = 0; half < 2; ++half) {
        const int lr = half * 4 + rr;
        const int r = r0 + lr;
        float a = 0.f;
        for (int p = eoff[lr]; p < eoff[lr + 1]; ++p) {
            a += msg[(size_t)eid2[p] * 64 + c];
        }
        float s = cb[c] + a * invd[r];
        const float* Ar = As + lr * 64;
#pragma unroll
        for (int k = 0; k < 64; k++) s += Ar[k] * Ws[k * 64 + c];
        hout[(size_t)r * 64 + c] = silu_f(s);
    }
}

// ---------------- fused mean-pool + head MLP ----------------
__global__ __launch_bounds__(256)
void k_poolhead(const float* __restrict__ h, const int* __restrict__ batch,
                const float* __restrict__ w1, const float* __restrict__ b1,
                const float* __restrict__ w2, const float* __restrict__ b2,
                float* __restrict__ out) {
    __shared__ float part[4 * 64];
    __shared__ float hrow[64];
    const int gidx = blockIdx.x;
    const int tid = threadIdx.x;
    const int r = tid >> 6, o = tid & 63;
    int lo = 0, hi = NN;
    while (lo < hi) { int m = (lo + hi) >> 1; if (batch[m] < gidx) lo = m + 1; else hi = m; }
    const int beg = lo;
    hi = NN;
    while (lo < hi) { int m = (lo + hi) >> 1; if (batch[m] < gidx + 1) lo = m + 1; else hi = m; }
    const int end = lo;
    float acc = 0.f;
    for (int n = beg + r; n < end; n += 4) acc += h[(size_t)n * 64 + o];
    part[r * 64 + o] = acc;
    __syncthreads();
    if (tid < 64) {
        const int cnt = end - beg;
        const float inv = (cnt > 0) ? 1.f / (float)cnt : 1.f;
        hrow[tid] = (part[tid] + part[64 + tid] + part[128 + tid] + part[192 + tid]) * inv;
    }
    __syncthreads();
    if (tid < 64) {
        float s = b1[tid];
#pragma unroll
        for (int k = 0; k < 64; ++k) s += hrow[k] * w1[k * 64 + tid];
        s = silu_f(s);
        float v = s * w2[tid];
#pragma unroll
        for (int d = 32; d > 0; d >>= 1) v += __shfl_down(v, d);
        if (tid == 0) out[gidx] = v + b2[0];
    }
}

extern "C" void kernel_launch(void* const* d_in, const int* in_sizes, int n_in,
                              void* d_out, int out_size, void* d_ws, size_t ws_size,
                              hipStream_t stream) {
    const float* x     = (const float*)d_in[0];
    const float* ea    = (const float*)d_in[1];
    const int*   ei    = (const int*)  d_in[2];
    const int*   batch = (const int*)  d_in[3];
    const float* pw    = (const float*)d_in[4];
    const float* pb    = (const float*)d_in[5];
    const float* ew1   = (const float*)d_in[6];
    const float* eb1   = (const float*)d_in[7];
    const float* ew2   = (const float*)d_in[8];
    const float* eb2   = (const float*)d_in[9];
    const float* rw    = (const float*)d_in[10];
    const float* cb    = (const float*)d_in[11];
    const float* hw1   = (const float*)d_in[12];
    const float* hb1   = (const float*)d_in[13];
    const float* hw2   = (const float*)d_in[14];
    const float* hb2   = (const float*)d_in[15];
    float* out = (float*)d_out;

    float* ws = (float*)d_ws;
    size_t off = 0;
    auto alloc = [&](size_t n) {
        float* p = ws + off;
        off += (n + 63) & ~(size_t)63;
        return p;
    };
    float* hA   = alloc((size_t)NN * 64);
    float* hBuf = alloc((size_t)NN * 64);
    float* msg  = alloc((size_t)NE * 64);
    float* invd = alloc(NN);
    int* off_s = (int*)alloc(NN + 1);
    int* off_d = (int*)alloc(NN + 1);
    int* cnt_s = (int*)alloc(NN);
    int* cnt_d = (int*)alloc(NN);
    int* cur_s = (int*)alloc(NN);
    int* cur_d = (int*)alloc(NN);
    int* eid_s = (int*)alloc(NE);
    int* eid_d = (int*)alloc(NE);
    short* packW = (short*)alloc(3 * PWL / 2 + 64);
    short* packH = (short*)alloc((size_t)NRT * 2 * 3 * WFRAG / 2 + 64);

    const size_t needG3 = (size_t)3 * NE * 64;
    bool batchG = (off + needG3 + 128) * sizeof(float) <= ws_size;
    float* gbuf = alloc(batchG ? needG3 : (size_t)NE * 64);

    hipMemsetAsync(cnt_s, 0, NN * sizeof(int), stream);
    hipMemsetAsync(cnt_d, 0, NN * sizeof(int), stream);

    k_hist<<<dim3((NE + 255) / 256), dim3(256), 0, stream>>>(ei, cnt_s, cnt_d);
    k_scan2<<<dim3(1), dim3(1024), 0, stream>>>(cnt_s, cnt_d, off_s, off_d,
                                                cur_s, cur_d, invd);
    k_fill<<<dim3((NE + 255) / 256), dim3(256), 0, stream>>>(ei, off_s, cur_s, eid_s);
    k_fill<<<dim3((NE + 255) / 256), dim3(256), 0, stream>>>(ei + NE, off_d, cur_d, eid_d);

    k_packw<<<dim3(NCT, 3), dim3(128), 0, stream>>>(ew2, eb2, packW);

    k_rowmm<64, false, true><<<dim3(NN / 4), dim3(256), 0, stream>>>(x, pw, pb, hA, NN);

    if (batchG) {
        k_gmm3<<<dim3(NE / 4, 3), dim3(256), 0, stream>>>(ea, ew1, eb1, gbuf);
    }

    float* hcur = hA;
    float* hnxt = hBuf;
    for (int l = 0; l < NLAYERS; l++) {
        float* gl = batchG ? gbuf + (size_t)l * NE * 64 : gbuf;
        if (!batchG) {
            k_rowmm<16, true, true><<<dim3(NE / 4), dim3(256), 0, stream>>>(
                ea, ew1 + (size_t)l * EDIM * 64, eb1 + (size_t)l * 64, gl, NE);
        }
        k_packh<<<dim3(NRT), dim3(128), 0, stream>>>(hcur, packH);
        k_msgfused<<<dim3(NRT, 4), dim3(512), 0, stream>>>(
            packH, packW + (size_t)l * PWL, gl, off_s, eid_s, msg);
        k_aggfin<<<dim3(NN / 8), dim3(256), 0, stream>>>(
            hcur, msg, off_d, eid_d, invd, rw + (size_t)l * 64 * 64,
            cb + (size_t)l * 64, hnxt);
        float* t = hcur; hcur = hnxt; hnxt = t;
    }

    k_poolhead<<<dim3(NGRAPH), dim3(256), 0, stream>>>(
        hcur, batch, hw1, hb1, hw2, hb2, out);
}